// Round 10
// baseline (395.275 us; speedup 1.0000x reference)
//
#include <hip/hip_runtime.h>
#include <cstdint>
#include <cstddef>

// B=2, S=2048, D=768, H=12, DH=64, T=64, R=50, FF=3072
// fp32 I/O, bf16 MFMA internals.
// R20: XCD-aware block swizzle (T1) on all GEMM dispatches. Default x-fastest
// linear id round-robins across 8 XCDs -> blocks sharing a B-weight-panel
// land on 8 different L2s (every XCD fills all N-panels). Swizzle
// tile=(lin&7)*cpx+lin>>3 gives each XCD a contiguous tile range (few full
// y-columns): B-fill/XCD drops ~7x. All GEMM xy-planes %8==0 -> bijective.
// Attn + GEMM inner loop untouched from R19 (dbuf, KS=2).

typedef __bf16 bf16;
typedef __bf16 bf16x8 __attribute__((ext_vector_type(8)));
typedef __bf16 bf16x4 __attribute__((ext_vector_type(4)));
typedef __bf16 bf16x2 __attribute__((ext_vector_type(2)));
typedef float  floatx4 __attribute__((ext_vector_type(4)));

__device__ __forceinline__ void glds16(const bf16* g, bf16* l) {
  __builtin_amdgcn_global_load_lds((const __attribute__((address_space(1))) void*)g,
                                   (__attribute__((address_space(3))) void*)l, 16, 0, 0);
}

__device__ __forceinline__ float fexp2(float x) {
  float r;
  asm("v_exp_f32 %0, %1" : "=v"(r) : "v"(x));
  return r;
}

// XCD swizzle: hw-linear id (x-fastest) -> tile id s.t. each XCD (lin%8) gets
// a contiguous tile range. Requires nwg%8==0 (all our grids satisfy this).
__device__ __forceinline__ void xcd_swizzle(int nbx, int nby, int& bx, int& by) {
  int lin = blockIdx.y * nbx + blockIdx.x;
  int cpx = (nbx * nby) >> 3;
  int tile = (lin & 7) * cpx + (lin >> 3);
  bx = tile % nbx;
  by = tile / nbx;
}

// ---------------------------------------------------------------------------
// Merged prep: blocks 0-8 bQKV concat, 9-14 bKV2 concat, 15-398 tag pad,
// 399-1934 X f32->bf16 precast.
__global__ __launch_bounds__(256) void k_prep_all(const float* __restrict__ sa_bq,
                                                  const float* __restrict__ sa_bk,
                                                  const float* __restrict__ sa_bv,
                                                  const float* __restrict__ ca_bk,
                                                  const float* __restrict__ ca_bv,
                                                  const float* __restrict__ tag,
                                                  const float* __restrict__ X,
                                                  float* __restrict__ bQKV,
                                                  float* __restrict__ bKV2,
                                                  bf16* __restrict__ tagp,
                                                  bf16* __restrict__ Xb) {
  int b = blockIdx.x, t = threadIdx.x;
  if (b < 9) {
    int i = b * 256 + t;
    int s = i / 768, j = i - s * 768;
    const float* p = s == 0 ? sa_bq : (s == 1 ? sa_bk : sa_bv);
    bQKV[i] = p[j];
  } else if (b < 15) {
    int i = (b - 9) * 256 + t;
    int s = i / 768, j = i - s * 768;
    bKV2[i] = s == 0 ? ca_bk[j] : ca_bv[j];
  } else if (b < 399) {
    int i = (b - 15) * 256 + t;
    if (i < 64 * 768) tagp[i] = (bf16)tag[i];
    else tagp[i] = (bf16)0.f;
  } else {
    int i = ((b - 399) * 256 + t) * 8;
    float4 a = *(const float4*)(X + i);
    float4 b4 = *(const float4*)(X + i + 4);
    bf16x8 o;
    o[0] = (bf16)a.x; o[1] = (bf16)a.y; o[2] = (bf16)a.z; o[3] = (bf16)a.w;
    o[4] = (bf16)b4.x; o[5] = (bf16)b4.y; o[6] = (bf16)b4.z; o[7] = (bf16)b4.w;
    *(bf16x8*)(Xb + i) = o;
  }
}

// ---------------------------------------------------------------------------
__device__ __forceinline__ void transpose_body(const float* __restrict__ W,
                                               bf16* __restrict__ Wt,
                                               int K, int N, int n0, int k0,
                                               bf16 (*tile)[72]) {
  int t = threadIdx.x;
  int r = t >> 2, cg = (t & 3) * 16;
  const float* src = W + (size_t)(k0 + r) * N + n0 + cg;
  float tmp[16];
  *(float4*)&tmp[0]  = *(const float4*)(src);
  *(float4*)&tmp[4]  = *(const float4*)(src + 4);
  *(float4*)&tmp[8]  = *(const float4*)(src + 8);
  *(float4*)&tmp[12] = *(const float4*)(src + 12);
#pragma unroll
  for (int i = 0; i < 16; ++i) tile[r][cg + i] = (bf16)tmp[i];
  __syncthreads();
  bf16* dst = Wt + (size_t)(n0 + r) * K + k0 + cg;
#pragma unroll
  for (int g = 0; g < 2; ++g) {
    bf16x8 pack;
#pragma unroll
    for (int i = 0; i < 8; ++i) pack[i] = tile[cg + g * 8 + i][r];
    *(bf16x8*)(dst + g * 8) = pack;
  }
}

__global__ __launch_bounds__(256) void k_transpose4(const float* __restrict__ W0,
                                                    const float* __restrict__ W1,
                                                    const float* __restrict__ W2w,
                                                    const float* __restrict__ W3,
                                                    bf16* __restrict__ Wt) {
  __shared__ bf16 tile[64][72];
  int z = blockIdx.z;
  const float* W = z == 0 ? W0 : (z == 1 ? W1 : (z == 2 ? W2w : W3));
  transpose_body(W, Wt + (size_t)z * 768 * 768, 768, 768,
                 blockIdx.x * 64, blockIdx.y * 64, tile);
}

// z=0: ff_w1 [768][3072] -> Wall [3072][768]; z=1: ff_w2 [3072][768] -> W2 [768][3072].
__global__ __launch_bounds__(256) void k_transpose_ff(const float* __restrict__ ff_w1,
                                                      const float* __restrict__ ff_w2,
                                                      bf16* __restrict__ Wall,
                                                      bf16* __restrict__ W2) {
  __shared__ bf16 tile[64][72];
  if (blockIdx.z == 0)
    transpose_body(ff_w1, Wall, 768, 3072, blockIdx.x * 64, blockIdx.y * 64, tile);
  else
    transpose_body(ff_w2, W2, 3072, 768, blockIdx.y * 64, blockIdx.x * 64, tile);
}

// ---------------------------------------------------------------------------
// GEMM core, LDS double-buffered: issue tile k+1 glds BEFORE MFMA on tile k;
// one barrier per K-step. As/Bs sized 2*KS*BM*32 / 2*KS*BN*32.
template <int BM, int BN, int KS, bool CF32>
__device__ __forceinline__ void gemm_body(const bf16* __restrict__ Ab,
                                          const bf16* __restrict__ Bt,
                                          const float* __restrict__ bias,
                                          void* __restrict__ Co,
                                          int N, int K, int ld, int act,
                                          int m0, int n0,
                                          bf16* __restrict__ As,
                                          bf16* __restrict__ Bs) {
  constexpr int MT = BM / 32;
  constexpr int NT = BN / 32;
  constexpr int KSTEP = 32 * KS;
  int tid = threadIdx.x;
  int lane = tid & 63, wave = tid >> 6;
  int l16 = lane & 15, quad = lane >> 4;
  int wm = wave & 1, wn = wave >> 1;
  int arow = tid >> 2, acol = (tid & 3) * 8;
  int ldst = arow * 32 + acol;  // = tid*8 elems (lane-contiguous glds pattern)

  const bf16* Ap = Ab + (size_t)(m0 + arow) * ld + acol;
  const bf16* Bp = Bt + (size_t)(n0 + arow) * ld + acol;

  auto stage = [&](int k, int buf) {
    bf16* Asb = As + buf * (KS * BM * 32);
    bf16* Bsb = Bs + buf * (KS * BN * 32);
#pragma unroll
    for (int ks = 0; ks < KS; ++ks) {
      glds16(Bp + k + ks * 32, Bsb + ks * BN * 32 + ldst);
      if constexpr (BN == 128) glds16(Bp + (size_t)64 * ld + k + ks * 32, Bsb + ks * BN * 32 + ldst + 2048);
      glds16(Ap + k + ks * 32, Asb + ks * BM * 32 + ldst);
      if constexpr (BM == 128) glds16(Ap + (size_t)64 * ld + k + ks * 32, Asb + ks * BM * 32 + ldst + 2048);
    }
  };

  floatx4 acc[MT][NT];
#pragma unroll
  for (int i = 0; i < MT; ++i)
#pragma unroll
    for (int j = 0; j < NT; ++j) acc[i][j] = floatx4{0.f, 0.f, 0.f, 0.f};

  stage(0, 0);
  __syncthreads();  // compiler drains vmcnt(0) before barrier -> buf0 ready

  int cur = 0;
  for (int k = 0; k < K; k += KSTEP) {
    // issue next tile's loads first (fly under this tile's MFMA)
    if (k + KSTEP < K) stage(k + KSTEP, cur ^ 1);
    bf16* Asb = As + cur * (KS * BM * 32);
    bf16* Bsb = Bs + cur * (KS * BN * 32);
#pragma unroll
    for (int ks = 0; ks < KS; ++ks) {
      bf16x8 a_frag[MT], b_frag[NT];
#pragma unroll
      for (int mt = 0; mt < MT; ++mt)
        a_frag[mt] = *(const bf16x8*)(Asb + ks * BM * 32 + (wm * (BM / 2) + mt * 16 + l16) * 32 + quad * 8);
#pragma unroll
      for (int nt = 0; nt < NT; ++nt)
        b_frag[nt] = *(const bf16x8*)(Bsb + ks * BN * 32 + (wn * (BN / 2) + nt * 16 + l16) * 32 + quad * 8);
#pragma unroll
      for (int mt = 0; mt < MT; ++mt)
#pragma unroll
        for (int nt = 0; nt < NT; ++nt)
          acc[mt][nt] = __builtin_amdgcn_mfma_f32_16x16x32_bf16(a_frag[mt], b_frag[nt], acc[mt][nt], 0, 0, 0);
    }
    __syncthreads();  // retires prefetch (latency mostly covered by MFMA)
    cur ^= 1;
  }

#pragma unroll
  for (int nt = 0; nt < NT; ++nt) {
    int col = n0 + wn * (BN / 2) + nt * 16 + l16;
    float bv = bias ? bias[col] : 0.f;
#pragma unroll
    for (int mt = 0; mt < MT; ++mt) {
#pragma unroll
      for (int r = 0; r < 4; ++r) {
        int row = m0 + wm * (BM / 2) + mt * 16 + quad * 4 + r;
        float v = acc[mt][nt][r] + bv;
        if (act) v = 0.5f * v * (1.f + erff(v * 0.70710678118654752f));
        if constexpr (CF32) ((float*)Co)[(size_t)row * N + col] = v;
        else ((bf16*)Co)[(size_t)row * N + col] = (bf16)v;
      }
    }
  }
}

// Standard GEMM; blockIdx.z = split-K chunk (z=0 -> Cv+bias, z=1 -> Cv2 raw).
// XCD-swizzled xy-plane (grid xy-size must be %8==0).
template <int BM, int BN, int KS, bool CF32>
__global__ __launch_bounds__(256) void k_gemm(const bf16* __restrict__ Ab,
                                              const bf16* __restrict__ Bt,
                                              const float* __restrict__ bias,
                                              void* __restrict__ Cv,
                                              void* __restrict__ Cv2,
                                              int N, int K, int ld, int act) {
  __shared__ bf16 As[2 * KS * BM * 32];
  __shared__ bf16 Bs[2 * KS * BN * 32];
  int z = blockIdx.z;
  int bx, by;
  xcd_swizzle(gridDim.x, gridDim.y, bx, by);
  gemm_body<BM, BN, KS, CF32>(Ab + z * K, Bt + z * K, z == 0 ? bias : nullptr,
                              z == 0 ? Cv : Cv2, N, K, ld, act,
                              bx * BM, by * BN, As, Bs);
}

// Q2 (z=0, full grid) + K2V2 (z=1, 48 blocks: m=(x&1), n=(x>>1)) in one dispatch.
__global__ __launch_bounds__(256) void k_gemm_q2kv(const bf16* __restrict__ A0,
                                                   const bf16* __restrict__ B0,
                                                   const float* __restrict__ bias0,
                                                   bf16* __restrict__ C0,
                                                   const bf16* __restrict__ A1,
                                                   const bf16* __restrict__ B1,
                                                   const float* __restrict__ bias1,
                                                   bf16* __restrict__ C1) {
  __shared__ bf16 As[2 * 2 * 64 * 32];
  __shared__ bf16 Bs[2 * 2 * 64 * 32];
  if (blockIdx.z == 0) {
    int bx, by;
    xcd_swizzle(gridDim.x, gridDim.y, bx, by);
    gemm_body<64, 64, 2, false>(A0, B0, bias0, C0, 768, 768, 768, 0,
                                bx * 64, by * 64, As, Bs);
  } else {
    if (blockIdx.y != 0 || blockIdx.x >= 48) return;
    gemm_body<64, 64, 2, false>(A1, B1, bias1, C1, 1536, 768, 768, 0,
                                (blockIdx.x & 1) * 64, (blockIdx.x >> 1) * 64, As, Bs);
  }
}

// ---------------------------------------------------------------------------
// MFMA flash attention, max-free streaming softmax. QBLK=64 rows per block.
// Wave w: q-half qh=w&1 (32 rows), key-half kh=w>>1 (32 keys/chunk).
// Q pre-scaled by log2e/8, fragments direct from global (no Qs LDS stage).
// K/V double-buffered in LDS: ONE barrier per chunk (R14).
__global__ __launch_bounds__(256) void k_attn_mfma(const bf16* __restrict__ Q, int ldq,
                                                   const bf16* __restrict__ Kp,
                                                   const bf16* __restrict__ Vp, int ldkv,
                                                   bf16* __restrict__ O,
                                                   int S, int Skv,
                                                   long long kv_bstride, int bandR) {
  const int NH = 12;
  int qt = blockIdx.x, bh = blockIdx.y;
  int bb = bh / NH, h = bh % NH;
  const bf16* Qb = Q + (size_t)bb * S * ldq + h * 64;
  const bf16* Kb = Kp + (size_t)bb * kv_bstride + h * 64;
  const bf16* Vb = Vp + (size_t)bb * kv_bstride + h * 64;
  bf16* Ob = O + (size_t)bb * S * 768 + h * 64;

  // LDS: Ks[2][64][72] @0 (18432), Vt[2][64][72] @18432 (18432),
  // Psw 4x[32][40] @36864 (10240) = 47104 B.
  // Epilogue overlay: Obuf[64][66] f32 @0 (16896), l0[64] @16896.
  __shared__ __align__(16) char smem[47104];
  float* Obuf = (float*)smem;
  float* l0_arr = (float*)(smem + 16896);

  int tid = threadIdx.x, wave = tid >> 6, lane = tid & 63;
  int quad = lane >> 4, l16 = lane & 15;
  int qh = wave & 1, kh = wave >> 1;
  bf16 (*Psw)[40] = (bf16(*)[40])(smem + 36864 + wave * 2560);

  const float C1 = 0.18033688f;   // log2(e)/8
  const float C2 = 1.44269504f;   // log2(e)

  int r = tid >> 2, cg = (tid & 3) * 16;  // K staging: 64 rows x 16 cols/lane
  int vk0 = 2 * (tid & 31);
  int vd0 = 8 * (tid >> 5);
  int vcol = (vk0 + 16 * (vd0 >> 4)) & 63;

  // Q fragments direct from global (once per block), pre-scaled by C1.
  bf16x8 aq[2][2];
#pragma unroll
  for (int mt = 0; mt < 2; ++mt) {
    const bf16* qsrc = Qb + (size_t)(qt * 64 + qh * 32 + mt * 16 + l16) * ldq;
#pragma unroll
    for (int ks = 0; ks < 2; ++ks) {
      bf16x8 t = *(const bf16x8*)(qsrc + ks * 32 + quad * 8);
#pragma unroll
      for (int e = 0; e < 8; ++e) t[e] = (bf16)((float)t[e] * C1);
      aq[mt][ks] = t;
    }
  }

  // prefetch regs for K/V chunk staging
  bf16x8 kr0, kr1, vr0, vr1;
  {
    const bf16* ksrc = Kb + (size_t)r * ldkv + cg;
    kr0 = *(const bf16x8*)ksrc;
    kr1 = *(const bf16x8*)(ksrc + 8);
    const bf16* vsrc = Vb + (size_t)vk0 * ldkv + vd0;
    vr0 = *(const bf16x8*)vsrc;
    vr1 = *(const bf16x8*)(vsrc + ldkv);
  }

  float l_part[2][4];
  floatx4 acc[2][4];
#pragma unroll
  for (int mt = 0; mt < 2; ++mt)
#pragma unroll
    for (int j = 0; j < 4; ++j) {
      l_part[mt][j] = 0.f;
      acc[mt][j] = floatx4{0.f, 0.f, 0.f, 0.f};
    }

  int qi0 = qt * 64 + qh * 32 + quad * 4;

  for (int kc = 0; kc < Skv; kc += 64) {
    int cur = (kc >> 6) & 1;
    bf16 (*Ks)[72] = (bf16(*)[72])(smem + cur * 9216);
    bf16 (*Vt)[72] = (bf16(*)[72])(smem + 18432 + cur * 9216);
    // write staged chunk to buf[cur] (prior reads fenced by iter c-1 barrier)
    *(bf16x8*)&Ks[r][cg] = kr0;
    *(bf16x8*)&Ks[r][cg + 8] = kr1;
#pragma unroll
    for (int e = 0; e < 8; ++e) {
      bf16x2 p; p[0] = vr0[e]; p[1] = vr1[e];
      *(bf16x2*)&Vt[vd0 + e][vcol] = p;
    }
    // issue next chunk's loads (fly under this chunk's compute)
    if (kc + 64 < Skv) {
      const bf16* ksrc = Kb + (size_t)(kc + 64 + r) * ldkv + cg;
      kr0 = *(const bf16x8*)ksrc;
      kr1 = *(const bf16x8*)(ksrc + 8);
      const bf16* vsrc = Vb + (size_t)(kc + 64 + vk0) * ldkv + vd0;
      vr0 = *(const bf16x8*)vsrc;
      vr1 = *(const bf16x8*)(vsrc + ldkv);
    }
    __syncthreads();

    floatx4 s[2][2];
    __builtin_amdgcn_s_setprio(1);
#pragma unroll
    for (int kt = 0; kt < 2; ++kt) {
      bf16x8 bk0 = *(const bf16x8*)&Ks[kh * 32 + kt * 16 + l16][quad * 8];
      bf16x8 bk1 = *(const bf16x8*)&Ks[kh * 32 + kt * 16 + l16][32 + quad * 8];
#pragma unroll
      for (int mt = 0; mt < 2; ++mt) {
        floatx4 c = {0.f, 0.f, 0.f, 0.f};
        c = __builtin_amdgcn_mfma_f32_16x16x32_bf16(aq[mt][0], bk0, c, 0, 0, 0);
        c = __builtin_amdgcn_mfma_f32_16x16x32_bf16(aq[mt][1], bk1, c, 0, 0, 0);
        s[mt][kt] = c;
      }
    }
    __builtin_amdgcn_s_setprio(0);

    bool masked = (bandR >= 0) && (kc <= qt * 64 + 63 + bandR) &&
                  (kc + 63 >= qt * 64 - bandR);
    if (masked) {
#pragma unroll
      for (int kt = 0; kt < 2; ++kt) {
        int kj = kc + kh * 32 + kt * 16 + l16;
        int colp = (kt * 16 + l16 + 8 * quad) & 31;
#pragma unroll
        for (int mt = 0; mt < 2; ++mt)
#pragma unroll
          for (int rr = 0; rr < 4; ++rr) {
            int d = qi0 + mt * 16 + rr - kj; if (d < 0) d = -d;
            float e = fexp2(s[mt][kt][rr] + (d <= bandR ? C2 : 0.f));
            l_part[mt][rr] += e;
            Psw[mt * 16 + quad * 4 + rr][colp] = (bf16)e;
          }
      }
    } else {
#pragma unroll
      for (int kt = 0; kt < 2; ++kt) {
        int colp = (kt * 16 + l16 + 8 * quad) & 31;
#pragma unroll
        for (int mt = 0; mt < 2; ++mt)
#pragma unroll
          for (int rr = 0; rr < 4; ++rr) {
            float e = fexp2(s[mt][kt][rr]);
            l_part[mt][rr] += e;
            Psw[mt * 16 + quad * 4 + rr][colp] = (bf16)e;
          }
      }
    }

    bf16x8 ap[2];
#pragma unroll
    for (int mt = 0; mt < 2; ++mt)
      ap[mt] = *(const bf16x8*)&Psw[mt * 16 + l16][8 * ((quad + (l16 >> 2)) & 3)];
    __builtin_amdgcn_s_setprio(1);
#pragma unroll
    for (int nt = 0; nt < 4; ++nt) {
      bf16x8 bv = *(const bf16x8*)&Vt[nt * 16 + l16][(kh * 32 + quad * 8 + 16 * nt) & 63];
#pragma unroll
      for (int mt = 0; mt < 2; ++mt)
        acc[mt][nt] = __builtin_amdgcn_mfma_f32_16x16x32_bf16(ap[mt], bv, acc[mt][nt], 0, 0, 0);
    }
    __builtin_amdgcn_s_setprio(0);
  }

  // ---- epilogue: reduce l within quad, combine key-halves via LDS ----
  float lr[2][4];
#pragma unroll
  for (int mt = 0; mt < 2; ++mt)
#pragma unroll
    for (int rr = 0; rr < 4; ++rr) {
      float t = l_part[mt][rr];
      t += __shfl_xor(t, 1);
      t += __shfl_xor(t, 2);
      t += __shfl_xor(t, 4);
      t += __shfl_xor(t, 8);
      lr[mt][rr] = t;
    }
  __syncthreads();
  if (kh == 0) {
#pragma unroll
    for (int mt = 0; mt < 2; ++mt)
#pragma unroll
      for (int nt = 0; nt < 4; ++nt)
#pragma unroll
        for (int rr = 0; rr < 4; ++rr)
          Obuf[(qh * 32 + mt * 16 + quad * 4 + rr) * 66 + nt * 16 + l16] = acc[mt][nt][rr];
    if (l16 == 0) {
#pragma unroll
      for (int mt = 0; mt < 2; ++mt)
#pragma unroll
        for (int rr = 0; rr < 4; ++rr)
          l0_arr[qh * 32 + mt * 16 + quad * 4 + rr] = lr[mt][rr];
    }
  }
  __syncthreads();
  if (kh == 1) {
#pragma unroll
    for (int mt = 0; mt < 2; ++mt)
#pragma unroll
      for (int rr = 0; rr < 4; ++rr) {
        int ql = qh * 32 + mt * 16 + quad * 4 + rr;
        float lt = lr[mt][rr] + l0_arr[ql];
        int qrow = qt * 64 + ql;
#pragma unroll
        for (int nt = 0; nt < 4; ++nt) {
          float o = (acc[mt][nt][rr] + Obuf[ql * 66 + nt * 16 + l16]) / lt;
          Ob[(size_t)qrow * 768 + nt * 16 + l16] = (bf16)o;
        }
      }
  }
}

// ---------------------------------------------------------------------------
// Y + X (+ optional f32 partial Y2) -> LayerNorm -> out.
template <typename TY, typename TR, typename TO>
__global__ __launch_bounds__(256) void k_add_ln(const TY* __restrict__ Y,
                                                const TR* __restrict__ X,
                                                const float* __restrict__ Y2,
                                                const float* __restrict__ g,
                                                const float* __restrict__ b,
                                                TO* __restrict__ out) {
  int wave = threadIdx.x >> 6, lane = threadIdx.x & 63;
  int row = blockIdx.x * 4 + wave;
  const TY* y = Y + (size_t)row * 768;
  const TR* x = X + (size_t)row * 768;
  float v[12];
  float s = 0.f, s2 = 0.f;
#pragma unroll
  for (int c = 0; c < 3; ++c) {
    int idx = c * 256 + lane * 4;
    float yv[4], xv[4];
    if constexpr (__is_same(TY, float)) {
      float4 t = *(const float4*)(y + idx);
      yv[0] = t.x; yv[1] = t.y; yv[2] = t.z; yv[3] = t.w;
    } else {
      bf16x4 t = *(const bf16x4*)(y + idx);
#pragma unroll
      for (int i = 0; i < 4; ++i) yv[i] = (float)t[i];
    }
    if constexpr (__is_same(TR, float)) {
      float4 t = *(const float4*)(x + idx);
      xv[0] = t.x; xv[1] = t.y; xv[2] = t.z; xv[3] = t.w;
    } else {
      bf16x4 t = *(const bf16x4*)(x + idx);
#pragma unroll
      for (int i = 0; i < 4; ++i) xv[i] = (float)t[i];
    }
    if (Y2 != nullptr) {
      float4 t2 = *(const float4*)(Y2 + (size_t)row * 768 + idx);
      xv[0] += t2.x; xv[1] += t2.y; xv[2] += t2.z; xv[3] += t2.w;
    }
#pragma unroll
    for (int i = 0; i < 4; ++i) {
      float t = yv[i] + xv[i];
      v[c * 4 + i] = t; s += t; s2 += t * t;
    }
  }
#pragma unroll
  for (int off = 32; off > 0; off >>= 1) { s += __shfl_xor(s, off); s2 += __shfl_xor(s2, off); }
  float mean = s * (1.f / 768.f);
  float var = fmaxf(s2 * (1.f / 768.f) - mean * mean, 0.f);
  float inv = rsqrtf(var + 1e-12f);
  TO* o = out + (size_t)row * 768;
#pragma unroll
  for (int c = 0; c < 3; ++c) {
    int idx = c * 256 + lane * 4;
    float4 gv = *(const float4*)(g + idx);
    float4 bv = *(const float4*)(b + idx);
    float r0 = (v[c * 4 + 0] - mean) * inv * gv.x + bv.x;
    float r1 = (v[c * 4 + 1] - mean) * inv * gv.y + bv.y;
    float r2 = (v[c * 4 + 2] - mean) * inv * gv.z + bv.z;
    float r3 = (v[c * 4 + 3] - mean) * inv * gv.w + bv.w;
    if constexpr (__is_same(TO, float)) {
      float4 ov = {r0, r1, r2, r3};
      *(float4*)(o + idx) = ov;
    } else {
      bf16x4 ov;
      ov[0] = (bf16)r0; ov[1] = (bf16)r1; ov[2] = (bf16)r2; ov[3] = (bf16)r3;
      *(bf16x4*)(o + idx) = ov;
    }
  }
}

// ---------------------------------------------------------------------------
extern "C" void kernel_launch(void* const* d_in, const int* in_sizes, int n_in,
                              void* d_out, int out_size, void* d_ws, size_t ws_size,
                              hipStream_t stream) {
  (void)in_sizes; (void)n_in; (void)out_size; (void)ws_size;
  const float* X     = (const float*)d_in[0];
  const float* tag   = (const float*)d_in[1];
  const float* sa_wq = (const float*)d_in[2];
  const float* sa_bq = (const float*)d_in[3];
  const float* sa_wk = (const float*)d_in[4];
  const float* sa_bk = (const float*)d_in[5];
  const float* sa_wv = (const float*)d_in[6];
  const float* sa_bv = (const float*)d_in[7];
  const float* sa_wo = (const float*)d_in[8];
  const float* sa_bo = (const float*)d_in[9];
  const float* sa_lg = (const float*)d_in[10];
  const float* sa_lb = (const float*)d_in[11];
  const float* ca_wq = (const float*)d_in[12];
  const float* ca_bq = (const float*)d_in[13];
  const float* ca_wk = (const float*)d_in[14];
  const float* ca_bk = (const float*)d_in[15];
  const float* ca_wv = (const float*)d_in[16];
  const float* ca_bv = (const float*)d_in[17];
  const float* ca_wo = (const float*)d_in[18];
  const float* ca_bo = (const float*)d_in[19];
  const float* ca_lg = (const float*)d_in[20];
  const float* ca_lb = (const float*)d_in[21];
  const float* ff_w1 = (const float*)d_in[22];
  const float* ff_b1 = (const float*)d_in[23];
  const float* ff_w2 = (const float*)d_in[24];
  const float* ff_b2 = (const float*)d_in[25];
  const float* ff_lg = (const float*)d_in[26];
  const float* ff_lb = (const float*)d_in[27];

  float* outf = (float*)d_out;
  bf16* outb = (bf16*)d_out;
  const size_t SLOT = (size_t)4096 * 768;

  // ---- ws: 34.60 MB ----
  bf16* BIG   = (bf16*)d_ws;                    // 4096x2304 (3 SLOTs)
  bf16* slotA = BIG + (size_t)4096 * 2304;      // residual chain
  bf16* Wall  = slotA + SLOT;                   // 3072x768
  bf16* W2    = Wall + (size_t)3072 * 768;      // 768x3072
  bf16* tagp  = W2;
  bf16* k2v2  = W2 + (size_t)128 * 768;
  float* bQKV = (float*)(W2 + (size_t)128 * 768 + (size_t)128 * 1536);
  float* bKV2 = bQKV + 2304;
  float* P1   = (float*)(BIG + 2 * SLOT);       // ff2 split-K partial (3rd SLOT)
  bf16*  Xb   = outb + SLOT;                    // X bf16, 2nd half of d_out

  dim3 blk(256);

  k_prep_all<<<dim3(1935), blk, 0, stream>>>(sa_bq, sa_bk, sa_bv, ca_bk, ca_bv, tag, X,
                                             bQKV, bKV2, tagp, Xb);

  // ---- self-attention ----
  k_transpose4<<<dim3(12, 12, 4), blk, 0, stream>>>(sa_wq, sa_wk, sa_wv, sa_wo, Wall);
  k_gemm<128, 64, 2, false><<<dim3(32, 36), blk, 0, stream>>>(Xb, Wall, bQKV, BIG, nullptr,
                                                              2304, 768, 768, 0);  // QKV
  k_attn_mfma<<<dim3(32, 24), blk, 0, stream>>>(BIG, 2304, BIG + 768, BIG + 1536, 2304,
                                                outb, 2048, 2048, (long long)2048 * 2304, 50);
  k_gemm<64, 64, 2, false><<<dim3(64, 12), blk, 0, stream>>>(outb, Wall + (size_t)2304 * 768,
                                                             sa_bo, slotA, nullptr,
                                                             768, 768, 768, 0);  // y1
  k_transpose4<<<dim3(12, 12, 4), blk, 0, stream>>>(ca_wq, ca_wk, ca_wv, ca_wo, Wall);
  k_add_ln<bf16, float, bf16><<<dim3(1024), blk, 0, stream>>>(slotA, X, nullptr, sa_lg, sa_lb, slotA);

  // ---- cross-attention ----
  // Q2 (z=0) + K2V2 (z=1, 48 blocks) in one dispatch.
  k_gemm_q2kv<<<dim3(64, 12, 2), blk, 0, stream>>>(slotA, Wall, ca_bq, BIG,
                                                   tagp, Wall + (size_t)768 * 768, bKV2, k2v2);
  k_attn_mfma<<<dim3(32, 24), blk, 0, stream>>>(BIG, 768, k2v2, k2v2 + 768, 1536,
                                                outb, 2048, 64, 0, -1);
  k_gemm<64, 64, 2, false><<<dim3(64, 12), blk, 0, stream>>>(outb, Wall + (size_t)2304 * 768,
                                                             ca_bo, BIG + SLOT, nullptr,
                                                             768, 768, 768, 0);  // y2
  k_add_ln<bf16, bf16, bf16><<<dim3(1024), blk, 0, stream>>>(BIG + SLOT, slotA, nullptr,
                                                             ca_lg, ca_lb, slotA);

  // ---- FFN: 2 M-chunks of 2048 rows via BIG (inter = first 2 SLOTs) ----
  k_transpose_ff<<<dim3(48, 12, 2), blk, 0, stream>>>(ff_w1, ff_w2, Wall, W2);
  for (int mc = 0; mc < 2; ++mc) {
    const bf16* a2 = slotA + (size_t)mc * 2048 * 768;
    float* yo = outf + (size_t)mc * 2048 * 768;
    k_gemm<128, 64, 2, false><<<dim3(16, 48), blk, 0, stream>>>(a2, Wall, ff_b1, BIG, nullptr,
                                                                3072, 768, 768, 1);  // gelu inter
    // ff2 split-K x2: z=0 -> yo (+bias), z=1 -> P1 (raw); summed in add_ln.
    k_gemm<64, 64, 2, true><<<dim3(32, 12, 2), blk, 0, stream>>>(BIG, W2, ff_b2, yo, P1,
                                                                 768, 1536, 3072, 0);
    k_add_ln<float, bf16, float><<<dim3(512), blk, 0, stream>>>(yo, a2, P1, ff_lg, ff_lb, yo);
  }
}

// Round 11
// 383.475 us; speedup vs baseline: 1.0308x; 1.0308x over previous
//
#include <hip/hip_runtime.h>
#include <cstdint>
#include <cstddef>

// B=2, S=2048, D=768, H=12, DH=64, T=64, R=50, FF=3072
// fp32 I/O, bf16 MFMA internals.
// R21: XCD swizzle reverted (R20: -9us — weight panels are L2/L3-resident so
// swizzle only broke default A-row locality). GEMMs = R19 state (dbuf KS=2).
// Attn: softmax denominator l via MFMA ones-trick — l[q]=sum_k P[q][k] is a
// matmul with ones-B: accl[mt]=mfma(ap[mt],ones,accl[mt]) (2 MFMA/chunk on
// the 17%-busy matrix pipe) replaces 16 VALU adds/chunk + the 8-shuffle
// epilogue reduce. l now sums bf16-quantized P (matches PV numerator).

typedef __bf16 bf16;
typedef __bf16 bf16x8 __attribute__((ext_vector_type(8)));
typedef __bf16 bf16x4 __attribute__((ext_vector_type(4)));
typedef __bf16 bf16x2 __attribute__((ext_vector_type(2)));
typedef float  floatx4 __attribute__((ext_vector_type(4)));

__device__ __forceinline__ void glds16(const bf16* g, bf16* l) {
  __builtin_amdgcn_global_load_lds((const __attribute__((address_space(1))) void*)g,
                                   (__attribute__((address_space(3))) void*)l, 16, 0, 0);
}

__device__ __forceinline__ float fexp2(float x) {
  float r;
  asm("v_exp_f32 %0, %1" : "=v"(r) : "v"(x));
  return r;
}

// ---------------------------------------------------------------------------
// Merged prep: blocks 0-8 bQKV concat, 9-14 bKV2 concat, 15-398 tag pad,
// 399-1934 X f32->bf16 precast.
__global__ __launch_bounds__(256) void k_prep_all(const float* __restrict__ sa_bq,
                                                  const float* __restrict__ sa_bk,
                                                  const float* __restrict__ sa_bv,
                                                  const float* __restrict__ ca_bk,
                                                  const float* __restrict__ ca_bv,
                                                  const float* __restrict__ tag,
                                                  const float* __restrict__ X,
                                                  float* __restrict__ bQKV,
                                                  float* __restrict__ bKV2,
                                                  bf16* __restrict__ tagp,
                                                  bf16* __restrict__ Xb) {
  int b = blockIdx.x, t = threadIdx.x;
  if (b < 9) {
    int i = b * 256 + t;
    int s = i / 768, j = i - s * 768;
    const float* p = s == 0 ? sa_bq : (s == 1 ? sa_bk : sa_bv);
    bQKV[i] = p[j];
  } else if (b < 15) {
    int i = (b - 9) * 256 + t;
    int s = i / 768, j = i - s * 768;
    bKV2[i] = s == 0 ? ca_bk[j] : ca_bv[j];
  } else if (b < 399) {
    int i = (b - 15) * 256 + t;
    if (i < 64 * 768) tagp[i] = (bf16)tag[i];
    else tagp[i] = (bf16)0.f;
  } else {
    int i = ((b - 399) * 256 + t) * 8;
    float4 a = *(const float4*)(X + i);
    float4 b4 = *(const float4*)(X + i + 4);
    bf16x8 o;
    o[0] = (bf16)a.x; o[1] = (bf16)a.y; o[2] = (bf16)a.z; o[3] = (bf16)a.w;
    o[4] = (bf16)b4.x; o[5] = (bf16)b4.y; o[6] = (bf16)b4.z; o[7] = (bf16)b4.w;
    *(bf16x8*)(Xb + i) = o;
  }
}

// ---------------------------------------------------------------------------
__device__ __forceinline__ void transpose_body(const float* __restrict__ W,
                                               bf16* __restrict__ Wt,
                                               int K, int N, int n0, int k0,
                                               bf16 (*tile)[72]) {
  int t = threadIdx.x;
  int r = t >> 2, cg = (t & 3) * 16;
  const float* src = W + (size_t)(k0 + r) * N + n0 + cg;
  float tmp[16];
  *(float4*)&tmp[0]  = *(const float4*)(src);
  *(float4*)&tmp[4]  = *(const float4*)(src + 4);
  *(float4*)&tmp[8]  = *(const float4*)(src + 8);
  *(float4*)&tmp[12] = *(const float4*)(src + 12);
#pragma unroll
  for (int i = 0; i < 16; ++i) tile[r][cg + i] = (bf16)tmp[i];
  __syncthreads();
  bf16* dst = Wt + (size_t)(n0 + r) * K + k0 + cg;
#pragma unroll
  for (int g = 0; g < 2; ++g) {
    bf16x8 pack;
#pragma unroll
    for (int i = 0; i < 8; ++i) pack[i] = tile[cg + g * 8 + i][r];
    *(bf16x8*)(dst + g * 8) = pack;
  }
}

__global__ __launch_bounds__(256) void k_transpose4(const float* __restrict__ W0,
                                                    const float* __restrict__ W1,
                                                    const float* __restrict__ W2w,
                                                    const float* __restrict__ W3,
                                                    bf16* __restrict__ Wt) {
  __shared__ bf16 tile[64][72];
  int z = blockIdx.z;
  const float* W = z == 0 ? W0 : (z == 1 ? W1 : (z == 2 ? W2w : W3));
  transpose_body(W, Wt + (size_t)z * 768 * 768, 768, 768,
                 blockIdx.x * 64, blockIdx.y * 64, tile);
}

// z=0: ff_w1 [768][3072] -> Wall [3072][768]; z=1: ff_w2 [3072][768] -> W2 [768][3072].
__global__ __launch_bounds__(256) void k_transpose_ff(const float* __restrict__ ff_w1,
                                                      const float* __restrict__ ff_w2,
                                                      bf16* __restrict__ Wall,
                                                      bf16* __restrict__ W2) {
  __shared__ bf16 tile[64][72];
  if (blockIdx.z == 0)
    transpose_body(ff_w1, Wall, 768, 3072, blockIdx.x * 64, blockIdx.y * 64, tile);
  else
    transpose_body(ff_w2, W2, 3072, 768, blockIdx.y * 64, blockIdx.x * 64, tile);
}

// ---------------------------------------------------------------------------
// GEMM core, LDS double-buffered: issue tile k+1 glds BEFORE MFMA on tile k;
// one barrier per K-step. As/Bs sized 2*KS*BM*32 / 2*KS*BN*32.
template <int BM, int BN, int KS, bool CF32>
__device__ __forceinline__ void gemm_body(const bf16* __restrict__ Ab,
                                          const bf16* __restrict__ Bt,
                                          const float* __restrict__ bias,
                                          void* __restrict__ Co,
                                          int N, int K, int ld, int act,
                                          int m0, int n0,
                                          bf16* __restrict__ As,
                                          bf16* __restrict__ Bs) {
  constexpr int MT = BM / 32;
  constexpr int NT = BN / 32;
  constexpr int KSTEP = 32 * KS;
  int tid = threadIdx.x;
  int lane = tid & 63, wave = tid >> 6;
  int l16 = lane & 15, quad = lane >> 4;
  int wm = wave & 1, wn = wave >> 1;
  int arow = tid >> 2, acol = (tid & 3) * 8;
  int ldst = arow * 32 + acol;  // = tid*8 elems (lane-contiguous glds pattern)

  const bf16* Ap = Ab + (size_t)(m0 + arow) * ld + acol;
  const bf16* Bp = Bt + (size_t)(n0 + arow) * ld + acol;

  auto stage = [&](int k, int buf) {
    bf16* Asb = As + buf * (KS * BM * 32);
    bf16* Bsb = Bs + buf * (KS * BN * 32);
#pragma unroll
    for (int ks = 0; ks < KS; ++ks) {
      glds16(Bp + k + ks * 32, Bsb + ks * BN * 32 + ldst);
      if constexpr (BN == 128) glds16(Bp + (size_t)64 * ld + k + ks * 32, Bsb + ks * BN * 32 + ldst + 2048);
      glds16(Ap + k + ks * 32, Asb + ks * BM * 32 + ldst);
      if constexpr (BM == 128) glds16(Ap + (size_t)64 * ld + k + ks * 32, Asb + ks * BM * 32 + ldst + 2048);
    }
  };

  floatx4 acc[MT][NT];
#pragma unroll
  for (int i = 0; i < MT; ++i)
#pragma unroll
    for (int j = 0; j < NT; ++j) acc[i][j] = floatx4{0.f, 0.f, 0.f, 0.f};

  stage(0, 0);
  __syncthreads();  // compiler drains vmcnt(0) before barrier -> buf0 ready

  int cur = 0;
  for (int k = 0; k < K; k += KSTEP) {
    // issue next tile's loads first (fly under this tile's MFMA)
    if (k + KSTEP < K) stage(k + KSTEP, cur ^ 1);
    bf16* Asb = As + cur * (KS * BM * 32);
    bf16* Bsb = Bs + cur * (KS * BN * 32);
#pragma unroll
    for (int ks = 0; ks < KS; ++ks) {
      bf16x8 a_frag[MT], b_frag[NT];
#pragma unroll
      for (int mt = 0; mt < MT; ++mt)
        a_frag[mt] = *(const bf16x8*)(Asb + ks * BM * 32 + (wm * (BM / 2) + mt * 16 + l16) * 32 + quad * 8);
#pragma unroll
      for (int nt = 0; nt < NT; ++nt)
        b_frag[nt] = *(const bf16x8*)(Bsb + ks * BN * 32 + (wn * (BN / 2) + nt * 16 + l16) * 32 + quad * 8);
#pragma unroll
      for (int mt = 0; mt < MT; ++mt)
#pragma unroll
        for (int nt = 0; nt < NT; ++nt)
          acc[mt][nt] = __builtin_amdgcn_mfma_f32_16x16x32_bf16(a_frag[mt], b_frag[nt], acc[mt][nt], 0, 0, 0);
    }
    __syncthreads();  // retires prefetch (latency mostly covered by MFMA)
    cur ^= 1;
  }

#pragma unroll
  for (int nt = 0; nt < NT; ++nt) {
    int col = n0 + wn * (BN / 2) + nt * 16 + l16;
    float bv = bias ? bias[col] : 0.f;
#pragma unroll
    for (int mt = 0; mt < MT; ++mt) {
#pragma unroll
      for (int r = 0; r < 4; ++r) {
        int row = m0 + wm * (BM / 2) + mt * 16 + quad * 4 + r;
        float v = acc[mt][nt][r] + bv;
        if (act) v = 0.5f * v * (1.f + erff(v * 0.70710678118654752f));
        if constexpr (CF32) ((float*)Co)[(size_t)row * N + col] = v;
        else ((bf16*)Co)[(size_t)row * N + col] = (bf16)v;
      }
    }
  }
}

// Standard GEMM; blockIdx.z = split-K chunk (z=0 -> Cv+bias, z=1 -> Cv2 raw).
template <int BM, int BN, int KS, bool CF32>
__global__ __launch_bounds__(256) void k_gemm(const bf16* __restrict__ Ab,
                                              const bf16* __restrict__ Bt,
                                              const float* __restrict__ bias,
                                              void* __restrict__ Cv,
                                              void* __restrict__ Cv2,
                                              int N, int K, int ld, int act) {
  __shared__ bf16 As[2 * KS * BM * 32];
  __shared__ bf16 Bs[2 * KS * BN * 32];
  int z = blockIdx.z;
  gemm_body<BM, BN, KS, CF32>(Ab + z * K, Bt + z * K, z == 0 ? bias : nullptr,
                              z == 0 ? Cv : Cv2, N, K, ld, act,
                              blockIdx.x * BM, blockIdx.y * BN, As, Bs);
}

// Q2 (z=0, full grid) + K2V2 (z=1, 48 blocks: m=(x&1), n=(x>>1)) in one dispatch.
__global__ __launch_bounds__(256) void k_gemm_q2kv(const bf16* __restrict__ A0,
                                                   const bf16* __restrict__ B0,
                                                   const float* __restrict__ bias0,
                                                   bf16* __restrict__ C0,
                                                   const bf16* __restrict__ A1,
                                                   const bf16* __restrict__ B1,
                                                   const float* __restrict__ bias1,
                                                   bf16* __restrict__ C1) {
  __shared__ bf16 As[2 * 2 * 64 * 32];
  __shared__ bf16 Bs[2 * 2 * 64 * 32];
  if (blockIdx.z == 0) {
    gemm_body<64, 64, 2, false>(A0, B0, bias0, C0, 768, 768, 768, 0,
                                blockIdx.x * 64, blockIdx.y * 64, As, Bs);
  } else {
    if (blockIdx.y != 0 || blockIdx.x >= 48) return;
    gemm_body<64, 64, 2, false>(A1, B1, bias1, C1, 1536, 768, 768, 0,
                                (blockIdx.x & 1) * 64, (blockIdx.x >> 1) * 64, As, Bs);
  }
}

// ---------------------------------------------------------------------------
// MFMA flash attention, max-free streaming softmax. QBLK=64 rows per block.
// Wave w: q-half qh=w&1 (32 rows), key-half kh=w>>1 (32 keys/chunk).
// Q pre-scaled by log2e/8, fragments direct from global (no Qs LDS stage).
// K/V double-buffered in LDS: ONE barrier per chunk (R14).
// l[q] computed via MFMA ones-trick (R21): accl = mfma(P-frag, ones, accl).
__global__ __launch_bounds__(256) void k_attn_mfma(const bf16* __restrict__ Q, int ldq,
                                                   const bf16* __restrict__ Kp,
                                                   const bf16* __restrict__ Vp, int ldkv,
                                                   bf16* __restrict__ O,
                                                   int S, int Skv,
                                                   long long kv_bstride, int bandR) {
  const int NH = 12;
  int qt = blockIdx.x, bh = blockIdx.y;
  int bb = bh / NH, h = bh % NH;
  const bf16* Qb = Q + (size_t)bb * S * ldq + h * 64;
  const bf16* Kb = Kp + (size_t)bb * kv_bstride + h * 64;
  const bf16* Vb = Vp + (size_t)bb * kv_bstride + h * 64;
  bf16* Ob = O + (size_t)bb * S * 768 + h * 64;

  // LDS: Ks[2][64][72] @0 (18432), Vt[2][64][72] @18432 (18432),
  // Psw 4x[32][40] @36864 (10240) = 47104 B.
  // Epilogue overlay: Obuf[64][66] f32 @0 (16896), l0[64] @16896.
  __shared__ __align__(16) char smem[47104];
  float* Obuf = (float*)smem;
  float* l0_arr = (float*)(smem + 16896);

  int tid = threadIdx.x, wave = tid >> 6, lane = tid & 63;
  int quad = lane >> 4, l16 = lane & 15;
  int qh = wave & 1, kh = wave >> 1;
  bf16 (*Psw)[40] = (bf16(*)[40])(smem + 36864 + wave * 2560);

  const float C1 = 0.18033688f;   // log2(e)/8
  const float C2 = 1.44269504f;   // log2(e)

  int r = tid >> 2, cg = (tid & 3) * 16;  // K staging: 64 rows x 16 cols/lane
  int vk0 = 2 * (tid & 31);
  int vd0 = 8 * (tid >> 5);
  int vcol = (vk0 + 16 * (vd0 >> 4)) & 63;

  // Q fragments direct from global (once per block), pre-scaled by C1.
  bf16x8 aq[2][2];
#pragma unroll
  for (int mt = 0; mt < 2; ++mt) {
    const bf16* qsrc = Qb + (size_t)(qt * 64 + qh * 32 + mt * 16 + l16) * ldq;
#pragma unroll
    for (int ks = 0; ks < 2; ++ks) {
      bf16x8 t = *(const bf16x8*)(qsrc + ks * 32 + quad * 8);
#pragma unroll
      for (int e = 0; e < 8; ++e) t[e] = (bf16)((float)t[e] * C1);
      aq[mt][ks] = t;
    }
  }

  // ones B-fragment for the l-MFMA (constant, no LDS)
  bf16x8 ones;
#pragma unroll
  for (int e = 0; e < 8; ++e) ones[e] = (bf16)1.f;

  // prefetch regs for K/V chunk staging
  bf16x8 kr0, kr1, vr0, vr1;
  {
    const bf16* ksrc = Kb + (size_t)r * ldkv + cg;
    kr0 = *(const bf16x8*)ksrc;
    kr1 = *(const bf16x8*)(ksrc + 8);
    const bf16* vsrc = Vb + (size_t)vk0 * ldkv + vd0;
    vr0 = *(const bf16x8*)vsrc;
    vr1 = *(const bf16x8*)(vsrc + ldkv);
  }

  floatx4 accl[2];
  floatx4 acc[2][4];
#pragma unroll
  for (int mt = 0; mt < 2; ++mt) {
    accl[mt] = floatx4{0.f, 0.f, 0.f, 0.f};
#pragma unroll
    for (int j = 0; j < 4; ++j) acc[mt][j] = floatx4{0.f, 0.f, 0.f, 0.f};
  }

  int qi0 = qt * 64 + qh * 32 + quad * 4;

  for (int kc = 0; kc < Skv; kc += 64) {
    int cur = (kc >> 6) & 1;
    bf16 (*Ks)[72] = (bf16(*)[72])(smem + cur * 9216);
    bf16 (*Vt)[72] = (bf16(*)[72])(smem + 18432 + cur * 9216);
    // write staged chunk to buf[cur] (prior reads fenced by iter c-1 barrier)
    *(bf16x8*)&Ks[r][cg] = kr0;
    *(bf16x8*)&Ks[r][cg + 8] = kr1;
#pragma unroll
    for (int e = 0; e < 8; ++e) {
      bf16x2 p; p[0] = vr0[e]; p[1] = vr1[e];
      *(bf16x2*)&Vt[vd0 + e][vcol] = p;
    }
    // issue next chunk's loads (fly under this chunk's compute)
    if (kc + 64 < Skv) {
      const bf16* ksrc = Kb + (size_t)(kc + 64 + r) * ldkv + cg;
      kr0 = *(const bf16x8*)ksrc;
      kr1 = *(const bf16x8*)(ksrc + 8);
      const bf16* vsrc = Vb + (size_t)(kc + 64 + vk0) * ldkv + vd0;
      vr0 = *(const bf16x8*)vsrc;
      vr1 = *(const bf16x8*)(vsrc + ldkv);
    }
    __syncthreads();

    floatx4 s[2][2];
    __builtin_amdgcn_s_setprio(1);
#pragma unroll
    for (int kt = 0; kt < 2; ++kt) {
      bf16x8 bk0 = *(const bf16x8*)&Ks[kh * 32 + kt * 16 + l16][quad * 8];
      bf16x8 bk1 = *(const bf16x8*)&Ks[kh * 32 + kt * 16 + l16][32 + quad * 8];
#pragma unroll
      for (int mt = 0; mt < 2; ++mt) {
        floatx4 c = {0.f, 0.f, 0.f, 0.f};
        c = __builtin_amdgcn_mfma_f32_16x16x32_bf16(aq[mt][0], bk0, c, 0, 0, 0);
        c = __builtin_amdgcn_mfma_f32_16x16x32_bf16(aq[mt][1], bk1, c, 0, 0, 0);
        s[mt][kt] = c;
      }
    }
    __builtin_amdgcn_s_setprio(0);

    bool masked = (bandR >= 0) && (kc <= qt * 64 + 63 + bandR) &&
                  (kc + 63 >= qt * 64 - bandR);
    if (masked) {
#pragma unroll
      for (int kt = 0; kt < 2; ++kt) {
        int kj = kc + kh * 32 + kt * 16 + l16;
        int colp = (kt * 16 + l16 + 8 * quad) & 31;
#pragma unroll
        for (int mt = 0; mt < 2; ++mt)
#pragma unroll
          for (int rr = 0; rr < 4; ++rr) {
            int d = qi0 + mt * 16 + rr - kj; if (d < 0) d = -d;
            float e = fexp2(s[mt][kt][rr] + (d <= bandR ? C2 : 0.f));
            Psw[mt * 16 + quad * 4 + rr][colp] = (bf16)e;
          }
      }
    } else {
#pragma unroll
      for (int kt = 0; kt < 2; ++kt) {
        int colp = (kt * 16 + l16 + 8 * quad) & 31;
#pragma unroll
        for (int mt = 0; mt < 2; ++mt)
#pragma unroll
          for (int rr = 0; rr < 4; ++rr) {
            float e = fexp2(s[mt][kt][rr]);
            Psw[mt * 16 + quad * 4 + rr][colp] = (bf16)e;
          }
      }
    }

    bf16x8 ap[2];
#pragma unroll
    for (int mt = 0; mt < 2; ++mt)
      ap[mt] = *(const bf16x8*)&Psw[mt * 16 + l16][8 * ((quad + (l16 >> 2)) & 3)];
    __builtin_amdgcn_s_setprio(1);
#pragma unroll
    for (int mt = 0; mt < 2; ++mt)
      accl[mt] = __builtin_amdgcn_mfma_f32_16x16x32_bf16(ap[mt], ones, accl[mt], 0, 0, 0);
#pragma unroll
    for (int nt = 0; nt < 4; ++nt) {
      bf16x8 bv = *(const bf16x8*)&Vt[nt * 16 + l16][(kh * 32 + quad * 8 + 16 * nt) & 63];
#pragma unroll
      for (int mt = 0; mt < 2; ++mt)
        acc[mt][nt] = __builtin_amdgcn_mfma_f32_16x16x32_bf16(ap[mt], bv, acc[mt][nt], 0, 0, 0);
    }
    __builtin_amdgcn_s_setprio(0);
  }

  // ---- epilogue: accl[mt][rr] = l[q] (replicated over cols); combine
  // key-halves via LDS ----
  __syncthreads();
  if (kh == 0) {
#pragma unroll
    for (int mt = 0; mt < 2; ++mt)
#pragma unroll
      for (int nt = 0; nt < 4; ++nt)
#pragma unroll
        for (int rr = 0; rr < 4; ++rr)
          Obuf[(qh * 32 + mt * 16 + quad * 4 + rr) * 66 + nt * 16 + l16] = acc[mt][nt][rr];
    if (l16 == 0) {
#pragma unroll
      for (int mt = 0; mt < 2; ++mt)
#pragma unroll
        for (int rr = 0; rr < 4; ++rr)
          l0_arr[qh * 32 + mt * 16 + quad * 4 + rr] = accl[mt][rr];
    }
  }
  __syncthreads();
  if (kh == 1) {
#pragma unroll
    for (int mt = 0; mt < 2; ++mt)
#pragma unroll
      for (int rr = 0; rr < 4; ++rr) {
        int ql = qh * 32 + mt * 16 + quad * 4 + rr;
        float lt = accl[mt][rr] + l0_arr[ql];
        int qrow = qt * 64 + ql;
#pragma unroll
        for (int nt = 0; nt < 4; ++nt) {
          float o = (acc[mt][nt][rr] + Obuf[ql * 66 + nt * 16 + l16]) / lt;
          Ob[(size_t)qrow * 768 + nt * 16 + l16] = (bf16)o;
        }
      }
  }
}

// ---------------------------------------------------------------------------
// Y + X (+ optional f32 partial Y2) -> LayerNorm -> out.
template <typename TY, typename TR, typename TO>
__global__ __launch_bounds__(256) void k_add_ln(const TY* __restrict__ Y,
                                                const TR* __restrict__ X,
                                                const float* __restrict__ Y2,
                                                const float* __restrict__ g,
                                                const float* __restrict__ b,
                                                TO* __restrict__ out) {
  int wave = threadIdx.x >> 6, lane = threadIdx.x & 63;
  int row = blockIdx.x * 4 + wave;
  const TY* y = Y + (size_t)row * 768;
  const TR* x = X + (size_t)row * 768;
  float v[12];
  float s = 0.f, s2 = 0.f;
#pragma unroll
  for (int c = 0; c < 3; ++c) {
    int idx = c * 256 + lane * 4;
    float yv[4], xv[4];
    if constexpr (__is_same(TY, float)) {
      float4 t = *(const float4*)(y + idx);
      yv[0] = t.x; yv[1] = t.y; yv[2] = t.z; yv[3] = t.w;
    } else {
      bf16x4 t = *(const bf16x4*)(y + idx);
#pragma unroll
      for (int i = 0; i < 4; ++i) yv[i] = (float)t[i];
    }
    if constexpr (__is_same(TR, float)) {
      float4 t = *(const float4*)(x + idx);
      xv[0] = t.x; xv[1] = t.y; xv[2] = t.z; xv[3] = t.w;
    } else {
      bf16x4 t = *(const bf16x4*)(x + idx);
#pragma unroll
      for (int i = 0; i < 4; ++i) xv[i] = (float)t[i];
    }
    if (Y2 != nullptr) {
      float4 t2 = *(const float4*)(Y2 + (size_t)row * 768 + idx);
      xv[0] += t2.x; xv[1] += t2.y; xv[2] += t2.z; xv[3] += t2.w;
    }
#pragma unroll
    for (int i = 0; i < 4; ++i) {
      float t = yv[i] + xv[i];
      v[c * 4 + i] = t; s += t; s2 += t * t;
    }
  }
#pragma unroll
  for (int off = 32; off > 0; off >>= 1) { s += __shfl_xor(s, off); s2 += __shfl_xor(s2, off); }
  float mean = s * (1.f / 768.f);
  float var = fmaxf(s2 * (1.f / 768.f) - mean * mean, 0.f);
  float inv = rsqrtf(var + 1e-12f);
  TO* o = out + (size_t)row * 768;
#pragma unroll
  for (int c = 0; c < 3; ++c) {
    int idx = c * 256 + lane * 4;
    float4 gv = *(const float4*)(g + idx);
    float4 bv = *(const float4*)(b + idx);
    float r0 = (v[c * 4 + 0] - mean) * inv * gv.x + bv.x;
    float r1 = (v[c * 4 + 1] - mean) * inv * gv.y + bv.y;
    float r2 = (v[c * 4 + 2] - mean) * inv * gv.z + bv.z;
    float r3 = (v[c * 4 + 3] - mean) * inv * gv.w + bv.w;
    if constexpr (__is_same(TO, float)) {
      float4 ov = {r0, r1, r2, r3};
      *(float4*)(o + idx) = ov;
    } else {
      bf16x4 ov;
      ov[0] = (bf16)r0; ov[1] = (bf16)r1; ov[2] = (bf16)r2; ov[3] = (bf16)r3;
      *(bf16x4*)(o + idx) = ov;
    }
  }
}

// ---------------------------------------------------------------------------
extern "C" void kernel_launch(void* const* d_in, const int* in_sizes, int n_in,
                              void* d_out, int out_size, void* d_ws, size_t ws_size,
                              hipStream_t stream) {
  (void)in_sizes; (void)n_in; (void)out_size; (void)ws_size;
  const float* X     = (const float*)d_in[0];
  const float* tag   = (const float*)d_in[1];
  const float* sa_wq = (const float*)d_in[2];
  const float* sa_bq = (const float*)d_in[3];
  const float* sa_wk = (const float*)d_in[4];
  const float* sa_bk = (const float*)d_in[5];
  const float* sa_wv = (const float*)d_in[6];
  const float* sa_bv = (const float*)d_in[7];
  const float* sa_wo = (const float*)d_in[8];
  const float* sa_bo = (const float*)d_in[9];
  const float* sa_lg = (const float*)d_in[10];
  const float* sa_lb = (const float*)d_in[11];
  const float* ca_wq = (const float*)d_in[12];
  const float* ca_bq = (const float*)d_in[13];
  const float* ca_wk = (const float*)d_in[14];
  const float* ca_bk = (const float*)d_in[15];
  const float* ca_wv = (const float*)d_in[16];
  const float* ca_bv = (const float*)d_in[17];
  const float* ca_wo = (const float*)d_in[18];
  const float* ca_bo = (const float*)d_in[19];
  const float* ca_lg = (const float*)d_in[20];
  const float* ca_lb = (const float*)d_in[21];
  const float* ff_w1 = (const float*)d_in[22];
  const float* ff_b1 = (const float*)d_in[23];
  const float* ff_w2 = (const float*)d_in[24];
  const float* ff_b2 = (const float*)d_in[25];
  const float* ff_lg = (const float*)d_in[26];
  const float* ff_lb = (const float*)d_in[27];

  float* outf = (float*)d_out;
  bf16* outb = (bf16*)d_out;
  const size_t SLOT = (size_t)4096 * 768;

  // ---- ws: 34.60 MB ----
  bf16* BIG   = (bf16*)d_ws;                    // 4096x2304 (3 SLOTs)
  bf16* slotA = BIG + (size_t)4096 * 2304;      // residual chain
  bf16* Wall  = slotA + SLOT;                   // 3072x768
  bf16* W2    = Wall + (size_t)3072 * 768;      // 768x3072
  bf16* tagp  = W2;
  bf16* k2v2  = W2 + (size_t)128 * 768;
  float* bQKV = (float*)(W2 + (size_t)128 * 768 + (size_t)128 * 1536);
  float* bKV2 = bQKV + 2304;
  float* P1   = (float*)(BIG + 2 * SLOT);       // ff2 split-K partial (3rd SLOT)
  bf16*  Xb   = outb + SLOT;                    // X bf16, 2nd half of d_out

  dim3 blk(256);

  k_prep_all<<<dim3(1935), blk, 0, stream>>>(sa_bq, sa_bk, sa_bv, ca_bk, ca_bv, tag, X,
                                             bQKV, bKV2, tagp, Xb);

  // ---- self-attention ----
  k_transpose4<<<dim3(12, 12, 4), blk, 0, stream>>>(sa_wq, sa_wk, sa_wv, sa_wo, Wall);
  k_gemm<128, 64, 2, false><<<dim3(32, 36), blk, 0, stream>>>(Xb, Wall, bQKV, BIG, nullptr,
                                                              2304, 768, 768, 0);  // QKV
  k_attn_mfma<<<dim3(32, 24), blk, 0, stream>>>(BIG, 2304, BIG + 768, BIG + 1536, 2304,
                                                outb, 2048, 2048, (long long)2048 * 2304, 50);
  k_gemm<64, 64, 2, false><<<dim3(64, 12), blk, 0, stream>>>(outb, Wall + (size_t)2304 * 768,
                                                             sa_bo, slotA, nullptr,
                                                             768, 768, 768, 0);  // y1
  k_transpose4<<<dim3(12, 12, 4), blk, 0, stream>>>(ca_wq, ca_wk, ca_wv, ca_wo, Wall);
  k_add_ln<bf16, float, bf16><<<dim3(1024), blk, 0, stream>>>(slotA, X, nullptr, sa_lg, sa_lb, slotA);

  // ---- cross-attention ----
  // Q2 (z=0) + K2V2 (z=1, 48 blocks) in one dispatch.
  k_gemm_q2kv<<<dim3(64, 12, 2), blk, 0, stream>>>(slotA, Wall, ca_bq, BIG,
                                                   tagp, Wall + (size_t)768 * 768, bKV2, k2v2);
  k_attn_mfma<<<dim3(32, 24), blk, 0, stream>>>(BIG, 768, k2v2, k2v2 + 768, 1536,
                                                outb, 2048, 64, 0, -1);
  k_gemm<64, 64, 2, false><<<dim3(64, 12), blk, 0, stream>>>(outb, Wall + (size_t)2304 * 768,
                                                             ca_bo, BIG + SLOT, nullptr,
                                                             768, 768, 768, 0);  // y2
  k_add_ln<bf16, bf16, bf16><<<dim3(1024), blk, 0, stream>>>(BIG + SLOT, slotA, nullptr,
                                                             ca_lg, ca_lb, slotA);

  // ---- FFN: 2 M-chunks of 2048 rows via BIG (inter = first 2 SLOTs) ----
  k_transpose_ff<<<dim3(48, 12, 2), blk, 0, stream>>>(ff_w1, ff_w2, Wall, W2);
  for (int mc = 0; mc < 2; ++mc) {
    const bf16* a2 = slotA + (size_t)mc * 2048 * 768;
    float* yo = outf + (size_t)mc * 2048 * 768;
    k_gemm<128, 64, 2, false><<<dim3(16, 48), blk, 0, stream>>>(a2, Wall, ff_b1, BIG, nullptr,
                                                                3072, 768, 768, 1);  // gelu inter
    // ff2 split-K x2: z=0 -> yo (+bias), z=1 -> P1 (raw); summed in add_ln.
    k_gemm<64, 64, 2, true><<<dim3(32, 12, 2), blk, 0, stream>>>(BIG, W2, ff_b2, yo, P1,
                                                                 768, 1536, 3072, 0);
    k_add_ln<float, bf16, float><<<dim3(512), blk, 0, stream>>>(yo, a2, P1, ff_lg, ff_lb, yo);
  }
}

// Round 12
// 379.975 us; speedup vs baseline: 1.0403x; 1.0092x over previous
//
#include <hip/hip_runtime.h>
#include <cstdint>
#include <cstddef>

// B=2, S=2048, D=768, H=12, DH=64, T=64, R=50, FF=3072
// fp32 I/O, bf16 MFMA internals.
// R22: attn staging rewrite (GEMMs/add_ln unchanged from R21):
//  - K: global_load_lds direct (2x16B/thread), LDS row-major [64][64] with
//    XOR swizzle byte^=((row&7)<<4) applied on BOTH sides (inverse-swizzled
//    per-lane global src, swizzled b128 read addr) -> conflict-free reads.
//  - V: global_load_lds into [4k][16d]-subtiled layout (16B global chunks
//    contiguous in LDS); PV B-fragments via ds_read_b64_tr_b16 (HW
//    transpose). Kills the reg-staged V transpose (8 packs + 8 scattered
//    ds_write per thread per chunk = main bank-conflict source).
//  - dbuf order: barrier -> prefetch c+1 into buf^1 -> compute c (R19
//    pattern). tr-read asm fenced by lgkmcnt(0)+sched_barrier(0).
//  - LDS 47104 -> 43008. l-MFMA ones-trick (R21) kept.

typedef __bf16 bf16;
typedef __bf16 bf16x8 __attribute__((ext_vector_type(8)));
typedef __bf16 bf16x4 __attribute__((ext_vector_type(4)));
typedef __bf16 bf16x2 __attribute__((ext_vector_type(2)));
typedef float  floatx4 __attribute__((ext_vector_type(4)));
typedef unsigned uint32x2 __attribute__((ext_vector_type(2)));

__device__ __forceinline__ void glds16(const bf16* g, bf16* l) {
  __builtin_amdgcn_global_load_lds((const __attribute__((address_space(1))) void*)g,
                                   (__attribute__((address_space(3))) void*)l, 16, 0, 0);
}

__device__ __forceinline__ float fexp2(float x) {
  float r;
  asm("v_exp_f32 %0, %1" : "=v"(r) : "v"(x));
  return r;
}

// ---------------------------------------------------------------------------
// Merged prep: blocks 0-8 bQKV concat, 9-14 bKV2 concat, 15-398 tag pad,
// 399-1934 X f32->bf16 precast.
__global__ __launch_bounds__(256) void k_prep_all(const float* __restrict__ sa_bq,
                                                  const float* __restrict__ sa_bk,
                                                  const float* __restrict__ sa_bv,
                                                  const float* __restrict__ ca_bk,
                                                  const float* __restrict__ ca_bv,
                                                  const float* __restrict__ tag,
                                                  const float* __restrict__ X,
                                                  float* __restrict__ bQKV,
                                                  float* __restrict__ bKV2,
                                                  bf16* __restrict__ tagp,
                                                  bf16* __restrict__ Xb) {
  int b = blockIdx.x, t = threadIdx.x;
  if (b < 9) {
    int i = b * 256 + t;
    int s = i / 768, j = i - s * 768;
    const float* p = s == 0 ? sa_bq : (s == 1 ? sa_bk : sa_bv);
    bQKV[i] = p[j];
  } else if (b < 15) {
    int i = (b - 9) * 256 + t;
    int s = i / 768, j = i - s * 768;
    bKV2[i] = s == 0 ? ca_bk[j] : ca_bv[j];
  } else if (b < 399) {
    int i = (b - 15) * 256 + t;
    if (i < 64 * 768) tagp[i] = (bf16)tag[i];
    else tagp[i] = (bf16)0.f;
  } else {
    int i = ((b - 399) * 256 + t) * 8;
    float4 a = *(const float4*)(X + i);
    float4 b4 = *(const float4*)(X + i + 4);
    bf16x8 o;
    o[0] = (bf16)a.x; o[1] = (bf16)a.y; o[2] = (bf16)a.z; o[3] = (bf16)a.w;
    o[4] = (bf16)b4.x; o[5] = (bf16)b4.y; o[6] = (bf16)b4.z; o[7] = (bf16)b4.w;
    *(bf16x8*)(Xb + i) = o;
  }
}

// ---------------------------------------------------------------------------
__device__ __forceinline__ void transpose_body(const float* __restrict__ W,
                                               bf16* __restrict__ Wt,
                                               int K, int N, int n0, int k0,
                                               bf16 (*tile)[72]) {
  int t = threadIdx.x;
  int r = t >> 2, cg = (t & 3) * 16;
  const float* src = W + (size_t)(k0 + r) * N + n0 + cg;
  float tmp[16];
  *(float4*)&tmp[0]  = *(const float4*)(src);
  *(float4*)&tmp[4]  = *(const float4*)(src + 4);
  *(float4*)&tmp[8]  = *(const float4*)(src + 8);
  *(float4*)&tmp[12] = *(const float4*)(src + 12);
#pragma unroll
  for (int i = 0; i < 16; ++i) tile[r][cg + i] = (bf16)tmp[i];
  __syncthreads();
  bf16* dst = Wt + (size_t)(n0 + r) * K + k0 + cg;
#pragma unroll
  for (int g = 0; g < 2; ++g) {
    bf16x8 pack;
#pragma unroll
    for (int i = 0; i < 8; ++i) pack[i] = tile[cg + g * 8 + i][r];
    *(bf16x8*)(dst + g * 8) = pack;
  }
}

__global__ __launch_bounds__(256) void k_transpose4(const float* __restrict__ W0,
                                                    const float* __restrict__ W1,
                                                    const float* __restrict__ W2w,
                                                    const float* __restrict__ W3,
                                                    bf16* __restrict__ Wt) {
  __shared__ bf16 tile[64][72];
  int z = blockIdx.z;
  const float* W = z == 0 ? W0 : (z == 1 ? W1 : (z == 2 ? W2w : W3));
  transpose_body(W, Wt + (size_t)z * 768 * 768, 768, 768,
                 blockIdx.x * 64, blockIdx.y * 64, tile);
}

// z=0: ff_w1 [768][3072] -> Wall [3072][768]; z=1: ff_w2 [3072][768] -> W2 [768][3072].
__global__ __launch_bounds__(256) void k_transpose_ff(const float* __restrict__ ff_w1,
                                                      const float* __restrict__ ff_w2,
                                                      bf16* __restrict__ Wall,
                                                      bf16* __restrict__ W2) {
  __shared__ bf16 tile[64][72];
  if (blockIdx.z == 0)
    transpose_body(ff_w1, Wall, 768, 3072, blockIdx.x * 64, blockIdx.y * 64, tile);
  else
    transpose_body(ff_w2, W2, 3072, 768, blockIdx.y * 64, blockIdx.x * 64, tile);
}

// ---------------------------------------------------------------------------
// GEMM core, LDS double-buffered: issue tile k+1 glds BEFORE MFMA on tile k;
// one barrier per K-step. As/Bs sized 2*KS*BM*32 / 2*KS*BN*32.
template <int BM, int BN, int KS, bool CF32>
__device__ __forceinline__ void gemm_body(const bf16* __restrict__ Ab,
                                          const bf16* __restrict__ Bt,
                                          const float* __restrict__ bias,
                                          void* __restrict__ Co,
                                          int N, int K, int ld, int act,
                                          int m0, int n0,
                                          bf16* __restrict__ As,
                                          bf16* __restrict__ Bs) {
  constexpr int MT = BM / 32;
  constexpr int NT = BN / 32;
  constexpr int KSTEP = 32 * KS;
  int tid = threadIdx.x;
  int lane = tid & 63, wave = tid >> 6;
  int l16 = lane & 15, quad = lane >> 4;
  int wm = wave & 1, wn = wave >> 1;
  int arow = tid >> 2, acol = (tid & 3) * 8;
  int ldst = arow * 32 + acol;  // = tid*8 elems (lane-contiguous glds pattern)

  const bf16* Ap = Ab + (size_t)(m0 + arow) * ld + acol;
  const bf16* Bp = Bt + (size_t)(n0 + arow) * ld + acol;

  auto stage = [&](int k, int buf) {
    bf16* Asb = As + buf * (KS * BM * 32);
    bf16* Bsb = Bs + buf * (KS * BN * 32);
#pragma unroll
    for (int ks = 0; ks < KS; ++ks) {
      glds16(Bp + k + ks * 32, Bsb + ks * BN * 32 + ldst);
      if constexpr (BN == 128) glds16(Bp + (size_t)64 * ld + k + ks * 32, Bsb + ks * BN * 32 + ldst + 2048);
      glds16(Ap + k + ks * 32, Asb + ks * BM * 32 + ldst);
      if constexpr (BM == 128) glds16(Ap + (size_t)64 * ld + k + ks * 32, Asb + ks * BM * 32 + ldst + 2048);
    }
  };

  floatx4 acc[MT][NT];
#pragma unroll
  for (int i = 0; i < MT; ++i)
#pragma unroll
    for (int j = 0; j < NT; ++j) acc[i][j] = floatx4{0.f, 0.f, 0.f, 0.f};

  stage(0, 0);
  __syncthreads();  // compiler drains vmcnt(0) before barrier -> buf0 ready

  int cur = 0;
  for (int k = 0; k < K; k += KSTEP) {
    // issue next tile's loads first (fly under this tile's MFMA)
    if (k + KSTEP < K) stage(k + KSTEP, cur ^ 1);
    bf16* Asb = As + cur * (KS * BM * 32);
    bf16* Bsb = Bs + cur * (KS * BN * 32);
#pragma unroll
    for (int ks = 0; ks < KS; ++ks) {
      bf16x8 a_frag[MT], b_frag[NT];
#pragma unroll
      for (int mt = 0; mt < MT; ++mt)
        a_frag[mt] = *(const bf16x8*)(Asb + ks * BM * 32 + (wm * (BM / 2) + mt * 16 + l16) * 32 + quad * 8);
#pragma unroll
      for (int nt = 0; nt < NT; ++nt)
        b_frag[nt] = *(const bf16x8*)(Bsb + ks * BN * 32 + (wn * (BN / 2) + nt * 16 + l16) * 32 + quad * 8);
#pragma unroll
      for (int mt = 0; mt < MT; ++mt)
#pragma unroll
        for (int nt = 0; nt < NT; ++nt)
          acc[mt][nt] = __builtin_amdgcn_mfma_f32_16x16x32_bf16(a_frag[mt], b_frag[nt], acc[mt][nt], 0, 0, 0);
    }
    __syncthreads();  // retires prefetch (latency mostly covered by MFMA)
    cur ^= 1;
  }

#pragma unroll
  for (int nt = 0; nt < NT; ++nt) {
    int col = n0 + wn * (BN / 2) + nt * 16 + l16;
    float bv = bias ? bias[col] : 0.f;
#pragma unroll
    for (int mt = 0; mt < MT; ++mt) {
#pragma unroll
      for (int r = 0; r < 4; ++r) {
        int row = m0 + wm * (BM / 2) + mt * 16 + quad * 4 + r;
        float v = acc[mt][nt][r] + bv;
        if (act) v = 0.5f * v * (1.f + erff(v * 0.70710678118654752f));
        if constexpr (CF32) ((float*)Co)[(size_t)row * N + col] = v;
        else ((bf16*)Co)[(size_t)row * N + col] = (bf16)v;
      }
    }
  }
}

// Standard GEMM; blockIdx.z = split-K chunk (z=0 -> Cv+bias, z=1 -> Cv2 raw).
template <int BM, int BN, int KS, bool CF32>
__global__ __launch_bounds__(256) void k_gemm(const bf16* __restrict__ Ab,
                                              const bf16* __restrict__ Bt,
                                              const float* __restrict__ bias,
                                              void* __restrict__ Cv,
                                              void* __restrict__ Cv2,
                                              int N, int K, int ld, int act) {
  __shared__ bf16 As[2 * KS * BM * 32];
  __shared__ bf16 Bs[2 * KS * BN * 32];
  int z = blockIdx.z;
  gemm_body<BM, BN, KS, CF32>(Ab + z * K, Bt + z * K, z == 0 ? bias : nullptr,
                              z == 0 ? Cv : Cv2, N, K, ld, act,
                              blockIdx.x * BM, blockIdx.y * BN, As, Bs);
}

// Q2 (z=0, full grid) + K2V2 (z=1, 48 blocks: m=(x&1), n=(x>>1)) in one dispatch.
__global__ __launch_bounds__(256) void k_gemm_q2kv(const bf16* __restrict__ A0,
                                                   const bf16* __restrict__ B0,
                                                   const float* __restrict__ bias0,
                                                   bf16* __restrict__ C0,
                                                   const bf16* __restrict__ A1,
                                                   const bf16* __restrict__ B1,
                                                   const float* __restrict__ bias1,
                                                   bf16* __restrict__ C1) {
  __shared__ bf16 As[2 * 2 * 64 * 32];
  __shared__ bf16 Bs[2 * 2 * 64 * 32];
  if (blockIdx.z == 0) {
    gemm_body<64, 64, 2, false>(A0, B0, bias0, C0, 768, 768, 768, 0,
                                blockIdx.x * 64, blockIdx.y * 64, As, Bs);
  } else {
    if (blockIdx.y != 0 || blockIdx.x >= 48) return;
    gemm_body<64, 64, 2, false>(A1, B1, bias1, C1, 1536, 768, 768, 0,
                                (blockIdx.x & 1) * 64, (blockIdx.x >> 1) * 64, As, Bs);
  }
}

// ---------------------------------------------------------------------------
// MFMA flash attention, max-free streaming softmax. QBLK=64 rows per block.
// Wave w: q-half qh=w&1 (32 rows), key-half kh=w>>1 (32 keys/chunk).
// Q pre-scaled by log2e/8, fragments direct from global.
// K/V staged via global_load_lds, double-buffered (one barrier/chunk):
//  - K: row-major [64][64] with XOR swizzle byte^=((row&7)<<4), applied on
//    both write (inverse-swizzled global src) and read (b128 addr).
//  - V: subtiled [slot][4k][16d]; slot(kb,db) = db*16 + (kb&1)*8 +
//    ((kb>>3)&1)*4 + ((kb>>1)&3) so tr-reads per quad walk consecutive
//    slots. PV B-frags via ds_read_b64_tr_b16 (lane vaddr + offset:N).
// l[q] via MFMA ones-trick (R21).
__global__ __launch_bounds__(256) void k_attn_mfma(const bf16* __restrict__ Q, int ldq,
                                                   const bf16* __restrict__ Kp,
                                                   const bf16* __restrict__ Vp, int ldkv,
                                                   bf16* __restrict__ O,
                                                   int S, int Skv,
                                                   long long kv_bstride, int bandR) {
  const int NH = 12;
  int qt = blockIdx.x, bh = blockIdx.y;
  int bb = bh / NH, h = bh % NH;
  const bf16* Qb = Q + (size_t)bb * S * ldq + h * 64;
  const bf16* Kb = Kp + (size_t)bb * kv_bstride + h * 64;
  const bf16* Vb = Vp + (size_t)bb * kv_bstride + h * 64;
  bf16* Ob = O + (size_t)bb * S * 768 + h * 64;

  // LDS: Ks[2][8192] @0, Vs[2][8192] @16384, Psw 4x[32][40] @32768 = 43008 B.
  // Epilogue overlay: Obuf[64][66] f32 @0 (16896), l0[64] @16896.
  __shared__ __align__(16) char smem[43008];
  float* Obuf = (float*)smem;
  float* l0_arr = (float*)(smem + 16896);

  int tid = threadIdx.x, wave = tid >> 6, lane = tid & 63;
  int quad = lane >> 4, l16 = lane & 15;
  int qh = wave & 1, kh = wave >> 1;
  bf16 (*Psw)[40] = (bf16(*)[40])(smem + 32768 + wave * 2560);

  const float C1 = 0.18033688f;   // log2(e)/8
  const float C2 = 1.44269504f;   // log2(e)

  // ---- staging maps: thread covers 2x16B for K and 2x16B for V ----
  int L0 = wave * 1024 + lane * 16;
  int L1 = L0 + 4096;
  // K: LDS byte (row, b) holds K[row][(b ^ ((row&7)<<4))/2]
  int krow0 = L0 >> 7, kcol0 = ((L0 & 127) ^ ((krow0 & 7) << 4)) >> 1;
  int krow1 = L1 >> 7, kcol1 = ((L1 & 127) ^ ((krow1 & 7) << 4)) >> 1;
  // V: elem E = slot*64 + (k&3)*16 + (d&15); slot -> (kb, db) inverse
  int vk0s, vd0s, vk1s, vd1s;
  {
    int slot = L0 >> 7;
    int kb = ((slot >> 2) & 1) * 8 + (slot & 3) * 2 + ((slot >> 3) & 1);
    vk0s = kb * 4 + ((L0 >> 5) & 3);
    vd0s = (slot >> 4) * 16 + ((L0 >> 1) & 8);
  }
  {
    int slot = L1 >> 7;
    int kb = ((slot >> 2) & 1) * 8 + (slot & 3) * 2 + ((slot >> 3) & 1);
    vk1s = kb * 4 + ((L1 >> 5) & 3);
    vd1s = (slot >> 4) * 16 + ((L1 >> 1) & 8);
  }

  // Q fragments direct from global (once per block), pre-scaled by C1.
  bf16x8 aq[2][2];
#pragma unroll
  for (int mt = 0; mt < 2; ++mt) {
    const bf16* qsrc = Qb + (size_t)(qt * 64 + qh * 32 + mt * 16 + l16) * ldq;
#pragma unroll
    for (int ks = 0; ks < 2; ++ks) {
      bf16x8 t = *(const bf16x8*)(qsrc + ks * 32 + quad * 8);
#pragma unroll
      for (int e = 0; e < 8; ++e) t[e] = (bf16)((float)t[e] * C1);
      aq[mt][ks] = t;
    }
  }

  // ones B-fragment for the l-MFMA (constant, no LDS)
  bf16x8 ones;
#pragma unroll
  for (int e = 0; e < 8; ++e) ones[e] = (bf16)1.f;

  // 32-bit LDS offset base for V tr-reads
  unsigned vbase = (unsigned)(uintptr_t)(__attribute__((address_space(3))) char*)(smem + 16384);
  unsigned vlane = (unsigned)(((kh * 4 + quad) * 64 + l16) * 2);

  auto stage = [&](int kcb, int buf) {
    char* kd = smem + buf * 8192;
    char* vd = smem + 16384 + buf * 8192;
    glds16(Kb + (size_t)(kcb + krow0) * ldkv + kcol0, (bf16*)(kd + L0));
    glds16(Kb + (size_t)(kcb + krow1) * ldkv + kcol1, (bf16*)(kd + L1));
    glds16(Vb + (size_t)(kcb + vk0s) * ldkv + vd0s, (bf16*)(vd + L0));
    glds16(Vb + (size_t)(kcb + vk1s) * ldkv + vd1s, (bf16*)(vd + L1));
  };

  floatx4 accl[2];
  floatx4 acc[2][4];
#pragma unroll
  for (int mt = 0; mt < 2; ++mt) {
    accl[mt] = floatx4{0.f, 0.f, 0.f, 0.f};
#pragma unroll
    for (int j = 0; j < 4; ++j) acc[mt][j] = floatx4{0.f, 0.f, 0.f, 0.f};
  }

  int qi0 = qt * 64 + qh * 32 + quad * 4;

  stage(0, 0);
  for (int kc = 0; kc < Skv; kc += 64) {
    int cur = (kc >> 6) & 1;
    __syncthreads();  // drains glds(kc) (vmcnt0) + fences buffer reuse
    if (kc + 64 < Skv) stage(kc + 64, cur ^ 1);  // buf^1 safe post-barrier

    const char* kbase = smem + cur * 8192;
    floatx4 s[2][2];
    __builtin_amdgcn_s_setprio(1);
#pragma unroll
    for (int kt = 0; kt < 2; ++kt) {
      int rowA = kh * 32 + kt * 16 + l16;
      int sw = (rowA & 7) << 4;
      bf16x8 bk0 = *(const bf16x8*)(kbase + rowA * 128 + ((quad * 16) ^ sw));
      bf16x8 bk1 = *(const bf16x8*)(kbase + rowA * 128 + ((quad * 16 + 64) ^ sw));
#pragma unroll
      for (int mt = 0; mt < 2; ++mt) {
        floatx4 c = {0.f, 0.f, 0.f, 0.f};
        c = __builtin_amdgcn_mfma_f32_16x16x32_bf16(aq[mt][0], bk0, c, 0, 0, 0);
        c = __builtin_amdgcn_mfma_f32_16x16x32_bf16(aq[mt][1], bk1, c, 0, 0, 0);
        s[mt][kt] = c;
      }
    }
    __builtin_amdgcn_s_setprio(0);

    bool masked = (bandR >= 0) && (kc <= qt * 64 + 63 + bandR) &&
                  (kc + 63 >= qt * 64 - bandR);
    if (masked) {
#pragma unroll
      for (int kt = 0; kt < 2; ++kt) {
        int kj = kc + kh * 32 + kt * 16 + l16;
        int colp = (kt * 16 + l16 + 8 * quad) & 31;
#pragma unroll
        for (int mt = 0; mt < 2; ++mt)
#pragma unroll
          for (int rr = 0; rr < 4; ++rr) {
            int d = qi0 + mt * 16 + rr - kj; if (d < 0) d = -d;
            float e = fexp2(s[mt][kt][rr] + (d <= bandR ? C2 : 0.f));
            Psw[mt * 16 + quad * 4 + rr][colp] = (bf16)e;
          }
      }
    } else {
#pragma unroll
      for (int kt = 0; kt < 2; ++kt) {
        int colp = (kt * 16 + l16 + 8 * quad) & 31;
#pragma unroll
        for (int mt = 0; mt < 2; ++mt)
#pragma unroll
          for (int rr = 0; rr < 4; ++rr) {
            float e = fexp2(s[mt][kt][rr]);
            Psw[mt * 16 + quad * 4 + rr][colp] = (bf16)e;
          }
      }
    }

    bf16x8 ap[2];
#pragma unroll
    for (int mt = 0; mt < 2; ++mt)
      ap[mt] = *(const bf16x8*)&Psw[mt * 16 + l16][8 * ((quad + (l16 >> 2)) & 3)];

    // V B-fragments via HW transpose read: lane vaddr = subtile col l16;
    // offsets walk (nt, r): nt*2048 + r*1024 bytes.
    unsigned va = vbase + (unsigned)(cur * 8192) + vlane;
    uint32x2 u0, u1, u2, u3, u4, u5, u6, u7;
    asm volatile("ds_read_b64_tr_b16 %0, %1 offset:0"    : "=v"(u0) : "v"(va));
    asm volatile("ds_read_b64_tr_b16 %0, %1 offset:1024" : "=v"(u1) : "v"(va));
    asm volatile("ds_read_b64_tr_b16 %0, %1 offset:2048" : "=v"(u2) : "v"(va));
    asm volatile("ds_read_b64_tr_b16 %0, %1 offset:3072" : "=v"(u3) : "v"(va));
    asm volatile("ds_read_b64_tr_b16 %0, %1 offset:4096" : "=v"(u4) : "v"(va));
    asm volatile("ds_read_b64_tr_b16 %0, %1 offset:5120" : "=v"(u5) : "v"(va));
    asm volatile("ds_read_b64_tr_b16 %0, %1 offset:6144" : "=v"(u6) : "v"(va));
    asm volatile("ds_read_b64_tr_b16 %0, %1 offset:7168" : "=v"(u7) : "v"(va));
    asm volatile("s_waitcnt lgkmcnt(0)" ::: "memory");
    __builtin_amdgcn_sched_barrier(0);

    bf16x4 vlo[4], vhi[4];
    vlo[0] = __builtin_bit_cast(bf16x4, u0); vhi[0] = __builtin_bit_cast(bf16x4, u1);
    vlo[1] = __builtin_bit_cast(bf16x4, u2); vhi[1] = __builtin_bit_cast(bf16x4, u3);
    vlo[2] = __builtin_bit_cast(bf16x4, u4); vhi[2] = __builtin_bit_cast(bf16x4, u5);
    vlo[3] = __builtin_bit_cast(bf16x4, u6); vhi[3] = __builtin_bit_cast(bf16x4, u7);

    __builtin_amdgcn_s_setprio(1);
#pragma unroll
    for (int mt = 0; mt < 2; ++mt)
      accl[mt] = __builtin_amdgcn_mfma_f32_16x16x32_bf16(ap[mt], ones, accl[mt], 0, 0, 0);
#pragma unroll
    for (int nt = 0; nt < 4; ++nt) {
      bf16x8 bv = __builtin_shufflevector(vlo[nt], vhi[nt], 0, 1, 2, 3, 4, 5, 6, 7);
#pragma unroll
      for (int mt = 0; mt < 2; ++mt)
        acc[mt][nt] = __builtin_amdgcn_mfma_f32_16x16x32_bf16(ap[mt], bv, acc[mt][nt], 0, 0, 0);
    }
    __builtin_amdgcn_s_setprio(0);
  }

  // ---- epilogue: accl[mt][rr] = l[q]; combine key-halves via LDS ----
  __syncthreads();
  if (kh == 0) {
#pragma unroll
    for (int mt = 0; mt < 2; ++mt)
#pragma unroll
      for (int nt = 0; nt < 4; ++nt)
#pragma unroll
        for (int rr = 0; rr < 4; ++rr)
          Obuf[(qh * 32 + mt * 16 + quad * 4 + rr) * 66 + nt * 16 + l16] = acc[mt][nt][rr];
    if (l16 == 0) {
#pragma unroll
      for (int mt = 0; mt < 2; ++mt)
#pragma unroll
        for (int rr = 0; rr < 4; ++rr)
          l0_arr[qh * 32 + mt * 16 + quad * 4 + rr] = accl[mt][rr];
    }
  }
  __syncthreads();
  if (kh == 1) {
#pragma unroll
    for (int mt = 0; mt < 2; ++mt)
#pragma unroll
      for (int rr = 0; rr < 4; ++rr) {
        int ql = qh * 32 + mt * 16 + quad * 4 + rr;
        float lt = accl[mt][rr] + l0_arr[ql];
        int qrow = qt * 64 + ql;
#pragma unroll
        for (int nt = 0; nt < 4; ++nt) {
          float o = (acc[mt][nt][rr] + Obuf[ql * 66 + nt * 16 + l16]) / lt;
          Ob[(size_t)qrow * 768 + nt * 16 + l16] = (bf16)o;
        }
      }
  }
}

// ---------------------------------------------------------------------------
// Y + X (+ optional f32 partial Y2) -> LayerNorm -> out.
template <typename TY, typename TR, typename TO>
__global__ __launch_bounds__(256) void k_add_ln(const TY* __restrict__ Y,
                                                const TR* __restrict__ X,
                                                const float* __restrict__ Y2,
                                                const float* __restrict__ g,
                                                const float* __restrict__ b,
                                                TO* __restrict__ out) {
  int wave = threadIdx.x >> 6, lane = threadIdx.x & 63;
  int row = blockIdx.x * 4 + wave;
  const TY* y = Y + (size_t)row * 768;
  const TR* x = X + (size_t)row * 768;
  float v[12];
  float s = 0.f, s2 = 0.f;
#pragma unroll
  for (int c = 0; c < 3; ++c) {
    int idx = c * 256 + lane * 4;
    float yv[4], xv[4];
    if constexpr (__is_same(TY, float)) {
      float4 t = *(const float4*)(y + idx);
      yv[0] = t.x; yv[1] = t.y; yv[2] = t.z; yv[3] = t.w;
    } else {
      bf16x4 t = *(const bf16x4*)(y + idx);
#pragma unroll
      for (int i = 0; i < 4; ++i) yv[i] = (float)t[i];
    }
    if constexpr (__is_same(TR, float)) {
      float4 t = *(const float4*)(x + idx);
      xv[0] = t.x; xv[1] = t.y; xv[2] = t.z; xv[3] = t.w;
    } else {
      bf16x4 t = *(const bf16x4*)(x + idx);
#pragma unroll
      for (int i = 0; i < 4; ++i) xv[i] = (float)t[i];
    }
    if (Y2 != nullptr) {
      float4 t2 = *(const float4*)(Y2 + (size_t)row * 768 + idx);
      xv[0] += t2.x; xv[1] += t2.y; xv[2] += t2.z; xv[3] += t2.w;
    }
#pragma unroll
    for (int i = 0; i < 4; ++i) {
      float t = yv[i] + xv[i];
      v[c * 4 + i] = t; s += t; s2 += t * t;
    }
  }
#pragma unroll
  for (int off = 32; off > 0; off >>= 1) { s += __shfl_xor(s, off); s2 += __shfl_xor(s2, off); }
  float mean = s * (1.f / 768.f);
  float var = fmaxf(s2 * (1.f / 768.f) - mean * mean, 0.f);
  float inv = rsqrtf(var + 1e-12f);
  TO* o = out + (size_t)row * 768;
#pragma unroll
  for (int c = 0; c < 3; ++c) {
    int idx = c * 256 + lane * 4;
    float4 gv = *(const float4*)(g + idx);
    float4 bv = *(const float4*)(b + idx);
    float r0 = (v[c * 4 + 0] - mean) * inv * gv.x + bv.x;
    float r1 = (v[c * 4 + 1] - mean) * inv * gv.y + bv.y;
    float r2 = (v[c * 4 + 2] - mean) * inv * gv.z + bv.z;
    float r3 = (v[c * 4 + 3] - mean) * inv * gv.w + bv.w;
    if constexpr (__is_same(TO, float)) {
      float4 ov = {r0, r1, r2, r3};
      *(float4*)(o + idx) = ov;
    } else {
      bf16x4 ov;
      ov[0] = (bf16)r0; ov[1] = (bf16)r1; ov[2] = (bf16)r2; ov[3] = (bf16)r3;
      *(bf16x4*)(o + idx) = ov;
    }
  }
}

// ---------------------------------------------------------------------------
extern "C" void kernel_launch(void* const* d_in, const int* in_sizes, int n_in,
                              void* d_out, int out_size, void* d_ws, size_t ws_size,
                              hipStream_t stream) {
  (void)in_sizes; (void)n_in; (void)out_size; (void)ws_size;
  const float* X     = (const float*)d_in[0];
  const float* tag   = (const float*)d_in[1];
  const float* sa_wq = (const float*)d_in[2];
  const float* sa_bq = (const float*)d_in[3];
  const float* sa_wk = (const float*)d_in[4];
  const float* sa_bk = (const float*)d_in[5];
  const float* sa_wv = (const float*)d_in[6];
  const float* sa_bv = (const float*)d_in[7];
  const float* sa_wo = (const float*)d_in[8];
  const float* sa_bo = (const float*)d_in[9];
  const float* sa_lg = (const float*)d_in[10];
  const float* sa_lb = (const float*)d_in[11];
  const float* ca_wq = (const float*)d_in[12];
  const float* ca_bq = (const float*)d_in[13];
  const float* ca_wk = (const float*)d_in[14];
  const float* ca_bk = (const float*)d_in[15];
  const float* ca_wv = (const float*)d_in[16];
  const float* ca_bv = (const float*)d_in[17];
  const float* ca_wo = (const float*)d_in[18];
  const float* ca_bo = (const float*)d_in[19];
  const float* ca_lg = (const float*)d_in[20];
  const float* ca_lb = (const float*)d_in[21];
  const float* ff_w1 = (const float*)d_in[22];
  const float* ff_b1 = (const float*)d_in[23];
  const float* ff_w2 = (const float*)d_in[24];
  const float* ff_b2 = (const float*)d_in[25];
  const float* ff_lg = (const float*)d_in[26];
  const float* ff_lb = (const float*)d_in[27];

  float* outf = (float*)d_out;
  bf16* outb = (bf16*)d_out;
  const size_t SLOT = (size_t)4096 * 768;

  // ---- ws: 34.60 MB ----
  bf16* BIG   = (bf16*)d_ws;                    // 4096x2304 (3 SLOTs)
  bf16* slotA = BIG + (size_t)4096 * 2304;      // residual chain
  bf16* Wall  = slotA + SLOT;                   // 3072x768
  bf16* W2    = Wall + (size_t)3072 * 768;      // 768x3072
  bf16* tagp  = W2;
  bf16* k2v2  = W2 + (size_t)128 * 768;
  float* bQKV = (float*)(W2 + (size_t)128 * 768 + (size_t)128 * 1536);
  float* bKV2 = bQKV + 2304;
  float* P1   = (float*)(BIG + 2 * SLOT);       // ff2 split-K partial (3rd SLOT)
  bf16*  Xb   = outb + SLOT;                    // X bf16, 2nd half of d_out

  dim3 blk(256);

  k_prep_all<<<dim3(1935), blk, 0, stream>>>(sa_bq, sa_bk, sa_bv, ca_bk, ca_bv, tag, X,
                                             bQKV, bKV2, tagp, Xb);

  // ---- self-attention ----
  k_transpose4<<<dim3(12, 12, 4), blk, 0, stream>>>(sa_wq, sa_wk, sa_wv, sa_wo, Wall);
  k_gemm<128, 64, 2, false><<<dim3(32, 36), blk, 0, stream>>>(Xb, Wall, bQKV, BIG, nullptr,
                                                              2304, 768, 768, 0);  // QKV
  k_attn_mfma<<<dim3(32, 24), blk, 0, stream>>>(BIG, 2304, BIG + 768, BIG + 1536, 2304,
                                                outb, 2048, 2048, (long long)2048 * 2304, 50);
  k_gemm<64, 64, 2, false><<<dim3(64, 12), blk, 0, stream>>>(outb, Wall + (size_t)2304 * 768,
                                                             sa_bo, slotA, nullptr,
                                                             768, 768, 768, 0);  // y1
  k_transpose4<<<dim3(12, 12, 4), blk, 0, stream>>>(ca_wq, ca_wk, ca_wv, ca_wo, Wall);
  k_add_ln<bf16, float, bf16><<<dim3(1024), blk, 0, stream>>>(slotA, X, nullptr, sa_lg, sa_lb, slotA);

  // ---- cross-attention ----
  // Q2 (z=0) + K2V2 (z=1, 48 blocks) in one dispatch.
  k_gemm_q2kv<<<dim3(64, 12, 2), blk, 0, stream>>>(slotA, Wall, ca_bq, BIG,
                                                   tagp, Wall + (size_t)768 * 768, bKV2, k2v2);
  k_attn_mfma<<<dim3(32, 24), blk, 0, stream>>>(BIG, 768, k2v2, k2v2 + 768, 1536,
                                                outb, 2048, 64, 0, -1);
  k_gemm<64, 64, 2, false><<<dim3(64, 12), blk, 0, stream>>>(outb, Wall + (size_t)2304 * 768,
                                                             ca_bo, BIG + SLOT, nullptr,
                                                             768, 768, 768, 0);  // y2
  k_add_ln<bf16, bf16, bf16><<<dim3(1024), blk, 0, stream>>>(BIG + SLOT, slotA, nullptr,
                                                             ca_lg, ca_lb, slotA);

  // ---- FFN: 2 M-chunks of 2048 rows via BIG (inter = first 2 SLOTs) ----
  k_transpose_ff<<<dim3(48, 12, 2), blk, 0, stream>>>(ff_w1, ff_w2, Wall, W2);
  for (int mc = 0; mc < 2; ++mc) {
    const bf16* a2 = slotA + (size_t)mc * 2048 * 768;
    float* yo = outf + (size_t)mc * 2048 * 768;
    k_gemm<128, 64, 2, false><<<dim3(16, 48), blk, 0, stream>>>(a2, Wall, ff_b1, BIG, nullptr,
                                                                3072, 768, 768, 1);  // gelu inter
    // ff2 split-K x2: z=0 -> yo (+bias), z=1 -> P1 (raw); summed in add_ln.
    k_gemm<64, 64, 2, true><<<dim3(32, 12, 2), blk, 0, stream>>>(BIG, W2, ff_b2, yo, P1,
                                                                 768, 1536, 3072, 0);
    k_add_ln<float, bf16, float><<<dim3(512), blk, 0, stream>>>(yo, a2, P1, ff_lg, ff_lb, yo);
  }
}

// Round 13
// 375.374 us; speedup vs baseline: 1.0530x; 1.0123x over previous
//
#include <hip/hip_runtime.h>
#include <cstdint>
#include <cstddef>

// B=2, S=2048, D=768, H=12, DH=64, T=64, R=50, FF=3072
// fp32 I/O, bf16 MFMA internals.
// R23: P round-trip via subtiled LDS + tr-read (same treatment R22 gave V):
//  - P stored [4k][16q]-subtiled, slot s(kb,qb)=qb*8+(kb&1)*4+(kb>>1).
//    Per (mt,kt) the 4 exp values are q-consecutive -> ONE ds_write_b64
//    (was 16 scalar ds_write_b16 + colp math).
//  - A-fragments via 4x ds_read_b64_tr_b16: slot walk base+quad with the
//    permutation gives P[q=l16][k=quad*8+p*4+j] ascending-k (byte-compatible
//    with old fragment). Order: writes -> sched_barrier -> tr-reads ->
//    lgkmcnt(0)+sched_barrier -> MFMA (per-wave DS FIFO + rule #18).
//  - Psw 10240->8192B; LDS 43008->40960. Rest identical to R22.

typedef __bf16 bf16;
typedef __bf16 bf16x8 __attribute__((ext_vector_type(8)));
typedef __bf16 bf16x4 __attribute__((ext_vector_type(4)));
typedef __bf16 bf16x2 __attribute__((ext_vector_type(2)));
typedef float  floatx4 __attribute__((ext_vector_type(4)));
typedef unsigned uint32x2 __attribute__((ext_vector_type(2)));

__device__ __forceinline__ void glds16(const bf16* g, bf16* l) {
  __builtin_amdgcn_global_load_lds((const __attribute__((address_space(1))) void*)g,
                                   (__attribute__((address_space(3))) void*)l, 16, 0, 0);
}

__device__ __forceinline__ float fexp2(float x) {
  float r;
  asm("v_exp_f32 %0, %1" : "=v"(r) : "v"(x));
  return r;
}

// ---------------------------------------------------------------------------
// Merged prep: blocks 0-8 bQKV concat, 9-14 bKV2 concat, 15-398 tag pad,
// 399-1934 X f32->bf16 precast.
__global__ __launch_bounds__(256) void k_prep_all(const float* __restrict__ sa_bq,
                                                  const float* __restrict__ sa_bk,
                                                  const float* __restrict__ sa_bv,
                                                  const float* __restrict__ ca_bk,
                                                  const float* __restrict__ ca_bv,
                                                  const float* __restrict__ tag,
                                                  const float* __restrict__ X,
                                                  float* __restrict__ bQKV,
                                                  float* __restrict__ bKV2,
                                                  bf16* __restrict__ tagp,
                                                  bf16* __restrict__ Xb) {
  int b = blockIdx.x, t = threadIdx.x;
  if (b < 9) {
    int i = b * 256 + t;
    int s = i / 768, j = i - s * 768;
    const float* p = s == 0 ? sa_bq : (s == 1 ? sa_bk : sa_bv);
    bQKV[i] = p[j];
  } else if (b < 15) {
    int i = (b - 9) * 256 + t;
    int s = i / 768, j = i - s * 768;
    bKV2[i] = s == 0 ? ca_bk[j] : ca_bv[j];
  } else if (b < 399) {
    int i = (b - 15) * 256 + t;
    if (i < 64 * 768) tagp[i] = (bf16)tag[i];
    else tagp[i] = (bf16)0.f;
  } else {
    int i = ((b - 399) * 256 + t) * 8;
    float4 a = *(const float4*)(X + i);
    float4 b4 = *(const float4*)(X + i + 4);
    bf16x8 o;
    o[0] = (bf16)a.x; o[1] = (bf16)a.y; o[2] = (bf16)a.z; o[3] = (bf16)a.w;
    o[4] = (bf16)b4.x; o[5] = (bf16)b4.y; o[6] = (bf16)b4.z; o[7] = (bf16)b4.w;
    *(bf16x8*)(Xb + i) = o;
  }
}

// ---------------------------------------------------------------------------
__device__ __forceinline__ void transpose_body(const float* __restrict__ W,
                                               bf16* __restrict__ Wt,
                                               int K, int N, int n0, int k0,
                                               bf16 (*tile)[72]) {
  int t = threadIdx.x;
  int r = t >> 2, cg = (t & 3) * 16;
  const float* src = W + (size_t)(k0 + r) * N + n0 + cg;
  float tmp[16];
  *(float4*)&tmp[0]  = *(const float4*)(src);
  *(float4*)&tmp[4]  = *(const float4*)(src + 4);
  *(float4*)&tmp[8]  = *(const float4*)(src + 8);
  *(float4*)&tmp[12] = *(const float4*)(src + 12);
#pragma unroll
  for (int i = 0; i < 16; ++i) tile[r][cg + i] = (bf16)tmp[i];
  __syncthreads();
  bf16* dst = Wt + (size_t)(n0 + r) * K + k0 + cg;
#pragma unroll
  for (int g = 0; g < 2; ++g) {
    bf16x8 pack;
#pragma unroll
    for (int i = 0; i < 8; ++i) pack[i] = tile[cg + g * 8 + i][r];
    *(bf16x8*)(dst + g * 8) = pack;
  }
}

__global__ __launch_bounds__(256) void k_transpose4(const float* __restrict__ W0,
                                                    const float* __restrict__ W1,
                                                    const float* __restrict__ W2w,
                                                    const float* __restrict__ W3,
                                                    bf16* __restrict__ Wt) {
  __shared__ bf16 tile[64][72];
  int z = blockIdx.z;
  const float* W = z == 0 ? W0 : (z == 1 ? W1 : (z == 2 ? W2w : W3));
  transpose_body(W, Wt + (size_t)z * 768 * 768, 768, 768,
                 blockIdx.x * 64, blockIdx.y * 64, tile);
}

// z=0: ff_w1 [768][3072] -> Wall [3072][768]; z=1: ff_w2 [3072][768] -> W2 [768][3072].
__global__ __launch_bounds__(256) void k_transpose_ff(const float* __restrict__ ff_w1,
                                                      const float* __restrict__ ff_w2,
                                                      bf16* __restrict__ Wall,
                                                      bf16* __restrict__ W2) {
  __shared__ bf16 tile[64][72];
  if (blockIdx.z == 0)
    transpose_body(ff_w1, Wall, 768, 3072, blockIdx.x * 64, blockIdx.y * 64, tile);
  else
    transpose_body(ff_w2, W2, 3072, 768, blockIdx.y * 64, blockIdx.x * 64, tile);
}

// ---------------------------------------------------------------------------
// GEMM core, LDS double-buffered: issue tile k+1 glds BEFORE MFMA on tile k;
// one barrier per K-step. As/Bs sized 2*KS*BM*32 / 2*KS*BN*32.
template <int BM, int BN, int KS, bool CF32>
__device__ __forceinline__ void gemm_body(const bf16* __restrict__ Ab,
                                          const bf16* __restrict__ Bt,
                                          const float* __restrict__ bias,
                                          void* __restrict__ Co,
                                          int N, int K, int ld, int act,
                                          int m0, int n0,
                                          bf16* __restrict__ As,
                                          bf16* __restrict__ Bs) {
  constexpr int MT = BM / 32;
  constexpr int NT = BN / 32;
  constexpr int KSTEP = 32 * KS;
  int tid = threadIdx.x;
  int lane = tid & 63, wave = tid >> 6;
  int l16 = lane & 15, quad = lane >> 4;
  int wm = wave & 1, wn = wave >> 1;
  int arow = tid >> 2, acol = (tid & 3) * 8;
  int ldst = arow * 32 + acol;  // = tid*8 elems (lane-contiguous glds pattern)

  const bf16* Ap = Ab + (size_t)(m0 + arow) * ld + acol;
  const bf16* Bp = Bt + (size_t)(n0 + arow) * ld + acol;

  auto stage = [&](int k, int buf) {
    bf16* Asb = As + buf * (KS * BM * 32);
    bf16* Bsb = Bs + buf * (KS * BN * 32);
#pragma unroll
    for (int ks = 0; ks < KS; ++ks) {
      glds16(Bp + k + ks * 32, Bsb + ks * BN * 32 + ldst);
      if constexpr (BN == 128) glds16(Bp + (size_t)64 * ld + k + ks * 32, Bsb + ks * BN * 32 + ldst + 2048);
      glds16(Ap + k + ks * 32, Asb + ks * BM * 32 + ldst);
      if constexpr (BM == 128) glds16(Ap + (size_t)64 * ld + k + ks * 32, Asb + ks * BM * 32 + ldst + 2048);
    }
  };

  floatx4 acc[MT][NT];
#pragma unroll
  for (int i = 0; i < MT; ++i)
#pragma unroll
    for (int j = 0; j < NT; ++j) acc[i][j] = floatx4{0.f, 0.f, 0.f, 0.f};

  stage(0, 0);
  __syncthreads();  // compiler drains vmcnt(0) before barrier -> buf0 ready

  int cur = 0;
  for (int k = 0; k < K; k += KSTEP) {
    // issue next tile's loads first (fly under this tile's MFMA)
    if (k + KSTEP < K) stage(k + KSTEP, cur ^ 1);
    bf16* Asb = As + cur * (KS * BM * 32);
    bf16* Bsb = Bs + cur * (KS * BN * 32);
#pragma unroll
    for (int ks = 0; ks < KS; ++ks) {
      bf16x8 a_frag[MT], b_frag[NT];
#pragma unroll
      for (int mt = 0; mt < MT; ++mt)
        a_frag[mt] = *(const bf16x8*)(Asb + ks * BM * 32 + (wm * (BM / 2) + mt * 16 + l16) * 32 + quad * 8);
#pragma unroll
      for (int nt = 0; nt < NT; ++nt)
        b_frag[nt] = *(const bf16x8*)(Bsb + ks * BN * 32 + (wn * (BN / 2) + nt * 16 + l16) * 32 + quad * 8);
#pragma unroll
      for (int mt = 0; mt < MT; ++mt)
#pragma unroll
        for (int nt = 0; nt < NT; ++nt)
          acc[mt][nt] = __builtin_amdgcn_mfma_f32_16x16x32_bf16(a_frag[mt], b_frag[nt], acc[mt][nt], 0, 0, 0);
    }
    __syncthreads();  // retires prefetch (latency mostly covered by MFMA)
    cur ^= 1;
  }

#pragma unroll
  for (int nt = 0; nt < NT; ++nt) {
    int col = n0 + wn * (BN / 2) + nt * 16 + l16;
    float bv = bias ? bias[col] : 0.f;
#pragma unroll
    for (int mt = 0; mt < MT; ++mt) {
#pragma unroll
      for (int r = 0; r < 4; ++r) {
        int row = m0 + wm * (BM / 2) + mt * 16 + quad * 4 + r;
        float v = acc[mt][nt][r] + bv;
        if (act) v = 0.5f * v * (1.f + erff(v * 0.70710678118654752f));
        if constexpr (CF32) ((float*)Co)[(size_t)row * N + col] = v;
        else ((bf16*)Co)[(size_t)row * N + col] = (bf16)v;
      }
    }
  }
}

// Standard GEMM; blockIdx.z = split-K chunk (z=0 -> Cv+bias, z=1 -> Cv2 raw).
template <int BM, int BN, int KS, bool CF32>
__global__ __launch_bounds__(256) void k_gemm(const bf16* __restrict__ Ab,
                                              const bf16* __restrict__ Bt,
                                              const float* __restrict__ bias,
                                              void* __restrict__ Cv,
                                              void* __restrict__ Cv2,
                                              int N, int K, int ld, int act) {
  __shared__ bf16 As[2 * KS * BM * 32];
  __shared__ bf16 Bs[2 * KS * BN * 32];
  int z = blockIdx.z;
  gemm_body<BM, BN, KS, CF32>(Ab + z * K, Bt + z * K, z == 0 ? bias : nullptr,
                              z == 0 ? Cv : Cv2, N, K, ld, act,
                              blockIdx.x * BM, blockIdx.y * BN, As, Bs);
}

// Q2 (z=0, full grid) + K2V2 (z=1, 48 blocks: m=(x&1), n=(x>>1)) in one dispatch.
__global__ __launch_bounds__(256) void k_gemm_q2kv(const bf16* __restrict__ A0,
                                                   const bf16* __restrict__ B0,
                                                   const float* __restrict__ bias0,
                                                   bf16* __restrict__ C0,
                                                   const bf16* __restrict__ A1,
                                                   const bf16* __restrict__ B1,
                                                   const float* __restrict__ bias1,
                                                   bf16* __restrict__ C1) {
  __shared__ bf16 As[2 * 2 * 64 * 32];
  __shared__ bf16 Bs[2 * 2 * 64 * 32];
  if (blockIdx.z == 0) {
    gemm_body<64, 64, 2, false>(A0, B0, bias0, C0, 768, 768, 768, 0,
                                blockIdx.x * 64, blockIdx.y * 64, As, Bs);
  } else {
    if (blockIdx.y != 0 || blockIdx.x >= 48) return;
    gemm_body<64, 64, 2, false>(A1, B1, bias1, C1, 1536, 768, 768, 0,
                                (blockIdx.x & 1) * 64, (blockIdx.x >> 1) * 64, As, Bs);
  }
}

// ---------------------------------------------------------------------------
// MFMA flash attention, max-free streaming softmax. QBLK=64 rows per block.
// Wave w: q-half qh=w&1 (32 rows), key-half kh=w>>1 (32 keys/chunk).
// Q pre-scaled by log2e/8, fragments direct from global.
// K/V staged via global_load_lds, double-buffered (one barrier/chunk):
//  - K: row-major [64][64], XOR swizzle byte^=((row&7)<<4) on both sides.
//  - V: [4k][16d] subtiles; PV B-frags via ds_read_b64_tr_b16.
// P: [4k][16q] subtiles, slot s(kb,qb)=qb*8+(kb&1)*4+(kb>>1); exp written
// as ds_write_b64 (4/chunk); A-frags via 4x ds_read_b64_tr_b16.
// l[q] via MFMA ones-trick (R21).
__global__ __launch_bounds__(256) void k_attn_mfma(const bf16* __restrict__ Q, int ldq,
                                                   const bf16* __restrict__ Kp,
                                                   const bf16* __restrict__ Vp, int ldkv,
                                                   bf16* __restrict__ O,
                                                   int S, int Skv,
                                                   long long kv_bstride, int bandR) {
  const int NH = 12;
  int qt = blockIdx.x, bh = blockIdx.y;
  int bb = bh / NH, h = bh % NH;
  const bf16* Qb = Q + (size_t)bb * S * ldq + h * 64;
  const bf16* Kb = Kp + (size_t)bb * kv_bstride + h * 64;
  const bf16* Vb = Vp + (size_t)bb * kv_bstride + h * 64;
  bf16* Ob = O + (size_t)bb * S * 768 + h * 64;

  // LDS: Ks[2][8192] @0, Vs[2][8192] @16384, P 4x2048 @32768 = 40960 B.
  // Epilogue overlay: Obuf[64][66] f32 @0 (16896), l0[64] @16896.
  __shared__ __align__(16) char smem[40960];
  float* Obuf = (float*)smem;
  float* l0_arr = (float*)(smem + 16896);

  int tid = threadIdx.x, wave = tid >> 6, lane = tid & 63;
  int quad = lane >> 4, l16 = lane & 15;
  int qh = wave & 1, kh = wave >> 1;
  char* pw = smem + 32768 + wave * 2048;  // wave-private P region

  const float C1 = 0.18033688f;   // log2(e)/8
  const float C2 = 1.44269504f;   // log2(e)

  // ---- staging maps: thread covers 2x16B for K and 2x16B for V ----
  int L0 = wave * 1024 + lane * 16;
  int L1 = L0 + 4096;
  // K: LDS byte (row, b) holds K[row][(b ^ ((row&7)<<4))/2]
  int krow0 = L0 >> 7, kcol0 = ((L0 & 127) ^ ((krow0 & 7) << 4)) >> 1;
  int krow1 = L1 >> 7, kcol1 = ((L1 & 127) ^ ((krow1 & 7) << 4)) >> 1;
  // V: elem E = slot*64 + (k&3)*16 + (d&15); slot -> (kb, db) inverse
  int vk0s, vd0s, vk1s, vd1s;
  {
    int slot = L0 >> 7;
    int kb = ((slot >> 2) & 1) * 8 + (slot & 3) * 2 + ((slot >> 3) & 1);
    vk0s = kb * 4 + ((L0 >> 5) & 3);
    vd0s = (slot >> 4) * 16 + ((L0 >> 1) & 8);
  }
  {
    int slot = L1 >> 7;
    int kb = ((slot >> 2) & 1) * 8 + (slot & 3) * 2 + ((slot >> 3) & 1);
    vk1s = kb * 4 + ((L1 >> 5) & 3);
    vd1s = (slot >> 4) * 16 + ((L1 >> 1) & 8);
  }

  // Q fragments direct from global (once per block), pre-scaled by C1.
  bf16x8 aq[2][2];
#pragma unroll
  for (int mt = 0; mt < 2; ++mt) {
    const bf16* qsrc = Qb + (size_t)(qt * 64 + qh * 32 + mt * 16 + l16) * ldq;
#pragma unroll
    for (int ks = 0; ks < 2; ++ks) {
      bf16x8 t = *(const bf16x8*)(qsrc + ks * 32 + quad * 8);
#pragma unroll
      for (int e = 0; e < 8; ++e) t[e] = (bf16)((float)t[e] * C1);
      aq[mt][ks] = t;
    }
  }

  // ones B-fragment for the l-MFMA (constant, no LDS)
  bf16x8 ones;
#pragma unroll
  for (int e = 0; e < 8; ++e) ones[e] = (bf16)1.f;

  // 32-bit LDS offset bases for tr-reads
  unsigned vbase = (unsigned)(uintptr_t)(__attribute__((address_space(3))) char*)(smem + 16384);
  unsigned vlane = (unsigned)(((kh * 4 + quad) * 64 + l16) * 2);
  unsigned pbase = (unsigned)(uintptr_t)(__attribute__((address_space(3))) char*)pw
                   + (unsigned)(quad * 128 + l16 * 2);
  // P write: slot s = mt*8 + ((l16>>2)&1)*4 + kt*2 + (l16>>3); byte =
  // s*128 + (l16&3)*32 + quad*8.
  int pw_off = ((l16 >> 2) & 1) * 512 + (l16 >> 3) * 128 + (l16 & 3) * 32 + quad * 8;

  auto stage = [&](int kcb, int buf) {
    char* kd = smem + buf * 8192;
    char* vd = smem + 16384 + buf * 8192;
    glds16(Kb + (size_t)(kcb + krow0) * ldkv + kcol0, (bf16*)(kd + L0));
    glds16(Kb + (size_t)(kcb + krow1) * ldkv + kcol1, (bf16*)(kd + L1));
    glds16(Vb + (size_t)(kcb + vk0s) * ldkv + vd0s, (bf16*)(vd + L0));
    glds16(Vb + (size_t)(kcb + vk1s) * ldkv + vd1s, (bf16*)(vd + L1));
  };

  floatx4 accl[2];
  floatx4 acc[2][4];
#pragma unroll
  for (int mt = 0; mt < 2; ++mt) {
    accl[mt] = floatx4{0.f, 0.f, 0.f, 0.f};
#pragma unroll
    for (int j = 0; j < 4; ++j) acc[mt][j] = floatx4{0.f, 0.f, 0.f, 0.f};
  }

  int qi0 = qt * 64 + qh * 32 + quad * 4;

  stage(0, 0);
  for (int kc = 0; kc < Skv; kc += 64) {
    int cur = (kc >> 6) & 1;
    __syncthreads();  // drains glds(kc) (vmcnt0) + fences buffer reuse
    if (kc + 64 < Skv) stage(kc + 64, cur ^ 1);  // buf^1 safe post-barrier

    const char* kbase = smem + cur * 8192;
    floatx4 s[2][2];
    __builtin_amdgcn_s_setprio(1);
#pragma unroll
    for (int kt = 0; kt < 2; ++kt) {
      int rowA = kh * 32 + kt * 16 + l16;
      int sw = (rowA & 7) << 4;
      bf16x8 bk0 = *(const bf16x8*)(kbase + rowA * 128 + ((quad * 16) ^ sw));
      bf16x8 bk1 = *(const bf16x8*)(kbase + rowA * 128 + ((quad * 16 + 64) ^ sw));
#pragma unroll
      for (int mt = 0; mt < 2; ++mt) {
        floatx4 c = {0.f, 0.f, 0.f, 0.f};
        c = __builtin_amdgcn_mfma_f32_16x16x32_bf16(aq[mt][0], bk0, c, 0, 0, 0);
        c = __builtin_amdgcn_mfma_f32_16x16x32_bf16(aq[mt][1], bk1, c, 0, 0, 0);
        s[mt][kt] = c;
      }
    }
    __builtin_amdgcn_s_setprio(0);

    bool masked = (bandR >= 0) && (kc <= qt * 64 + 63 + bandR) &&
                  (kc + 63 >= qt * 64 - bandR);
    if (masked) {
#pragma unroll
      for (int kt = 0; kt < 2; ++kt) {
        int kj = kc + kh * 32 + kt * 16 + l16;
#pragma unroll
        for (int mt = 0; mt < 2; ++mt) {
          bf16x4 pv;
#pragma unroll
          for (int rr = 0; rr < 4; ++rr) {
            int d = qi0 + mt * 16 + rr - kj; if (d < 0) d = -d;
            pv[rr] = (bf16)fexp2(s[mt][kt][rr] + (d <= bandR ? C2 : 0.f));
          }
          *(bf16x4*)(pw + mt * 1024 + kt * 256 + pw_off) = pv;
        }
      }
    } else {
#pragma unroll
      for (int kt = 0; kt < 2; ++kt)
#pragma unroll
        for (int mt = 0; mt < 2; ++mt) {
          bf16x4 pv;
#pragma unroll
          for (int rr = 0; rr < 4; ++rr)
            pv[rr] = (bf16)fexp2(s[mt][kt][rr]);
          *(bf16x4*)(pw + mt * 1024 + kt * 256 + pw_off) = pv;
        }
    }
    __builtin_amdgcn_sched_barrier(0);  // pin P writes before tr-reads

    // A-fragments (P) + B-fragments (V) via HW transpose reads.
    uint32x2 q0, q1, q2, q3;
    asm volatile("ds_read_b64_tr_b16 %0, %1 offset:0"    : "=v"(q0) : "v"(pbase));
    asm volatile("ds_read_b64_tr_b16 %0, %1 offset:512"  : "=v"(q1) : "v"(pbase));
    asm volatile("ds_read_b64_tr_b16 %0, %1 offset:1024" : "=v"(q2) : "v"(pbase));
    asm volatile("ds_read_b64_tr_b16 %0, %1 offset:1536" : "=v"(q3) : "v"(pbase));
    unsigned va = vbase + (unsigned)(cur * 8192) + vlane;
    uint32x2 u0, u1, u2, u3, u4, u5, u6, u7;
    asm volatile("ds_read_b64_tr_b16 %0, %1 offset:0"    : "=v"(u0) : "v"(va));
    asm volatile("ds_read_b64_tr_b16 %0, %1 offset:1024" : "=v"(u1) : "v"(va));
    asm volatile("ds_read_b64_tr_b16 %0, %1 offset:2048" : "=v"(u2) : "v"(va));
    asm volatile("ds_read_b64_tr_b16 %0, %1 offset:3072" : "=v"(u3) : "v"(va));
    asm volatile("ds_read_b64_tr_b16 %0, %1 offset:4096" : "=v"(u4) : "v"(va));
    asm volatile("ds_read_b64_tr_b16 %0, %1 offset:5120" : "=v"(u5) : "v"(va));
    asm volatile("ds_read_b64_tr_b16 %0, %1 offset:6144" : "=v"(u6) : "v"(va));
    asm volatile("ds_read_b64_tr_b16 %0, %1 offset:7168" : "=v"(u7) : "v"(va));
    asm volatile("s_waitcnt lgkmcnt(0)" ::: "memory");
    __builtin_amdgcn_sched_barrier(0);

    bf16x8 ap[2];
    ap[0] = __builtin_shufflevector(__builtin_bit_cast(bf16x4, q0),
                                    __builtin_bit_cast(bf16x4, q1), 0, 1, 2, 3, 4, 5, 6, 7);
    ap[1] = __builtin_shufflevector(__builtin_bit_cast(bf16x4, q2),
                                    __builtin_bit_cast(bf16x4, q3), 0, 1, 2, 3, 4, 5, 6, 7);
    bf16x4 vlo[4], vhi[4];
    vlo[0] = __builtin_bit_cast(bf16x4, u0); vhi[0] = __builtin_bit_cast(bf16x4, u1);
    vlo[1] = __builtin_bit_cast(bf16x4, u2); vhi[1] = __builtin_bit_cast(bf16x4, u3);
    vlo[2] = __builtin_bit_cast(bf16x4, u4); vhi[2] = __builtin_bit_cast(bf16x4, u5);
    vlo[3] = __builtin_bit_cast(bf16x4, u6); vhi[3] = __builtin_bit_cast(bf16x4, u7);

    __builtin_amdgcn_s_setprio(1);
#pragma unroll
    for (int mt = 0; mt < 2; ++mt)
      accl[mt] = __builtin_amdgcn_mfma_f32_16x16x32_bf16(ap[mt], ones, accl[mt], 0, 0, 0);
#pragma unroll
    for (int nt = 0; nt < 4; ++nt) {
      bf16x8 bv = __builtin_shufflevector(vlo[nt], vhi[nt], 0, 1, 2, 3, 4, 5, 6, 7);
#pragma unroll
      for (int mt = 0; mt < 2; ++mt)
        acc[mt][nt] = __builtin_amdgcn_mfma_f32_16x16x32_bf16(ap[mt], bv, acc[mt][nt], 0, 0, 0);
    }
    __builtin_amdgcn_s_setprio(0);
  }

  // ---- epilogue: accl[mt][rr] = l[q]; combine key-halves via LDS ----
  __syncthreads();
  if (kh == 0) {
#pragma unroll
    for (int mt = 0; mt < 2; ++mt)
#pragma unroll
      for (int nt = 0; nt < 4; ++nt)
#pragma unroll
        for (int rr = 0; rr < 4; ++rr)
          Obuf[(qh * 32 + mt * 16 + quad * 4 + rr) * 66 + nt * 16 + l16] = acc[mt][nt][rr];
    if (l16 == 0) {
#pragma unroll
      for (int mt = 0; mt < 2; ++mt)
#pragma unroll
        for (int rr = 0; rr < 4; ++rr)
          l0_arr[qh * 32 + mt * 16 + quad * 4 + rr] = accl[mt][rr];
    }
  }
  __syncthreads();
  if (kh == 1) {
#pragma unroll
    for (int mt = 0; mt < 2; ++mt)
#pragma unroll
      for (int rr = 0; rr < 4; ++rr) {
        int ql = qh * 32 + mt * 16 + quad * 4 + rr;
        float lt = accl[mt][rr] + l0_arr[ql];
        int qrow = qt * 64 + ql;
#pragma unroll
        for (int nt = 0; nt < 4; ++nt) {
          float o = (acc[mt][nt][rr] + Obuf[ql * 66 + nt * 16 + l16]) / lt;
          Ob[(size_t)qrow * 768 + nt * 16 + l16] = (bf16)o;
        }
      }
  }
}

// ---------------------------------------------------------------------------
// Y + X (+ optional f32 partial Y2) -> LayerNorm -> out.
template <typename TY, typename TR, typename TO>
__global__ __launch_bounds__(256) void k_add_ln(const TY* __restrict__ Y,
                                                const TR* __restrict__ X,
                                                const float* __restrict__ Y2,
                                                const float* __restrict__ g,
                                                const float* __restrict__ b,
                                                TO* __restrict__ out) {
  int wave = threadIdx.x >> 6, lane = threadIdx.x & 63;
  int row = blockIdx.x * 4 + wave;
  const TY* y = Y + (size_t)row * 768;
  const TR* x = X + (size_t)row * 768;
  float v[12];
  float s = 0.f, s2 = 0.f;
#pragma unroll
  for (int c = 0; c < 3; ++c) {
    int idx = c * 256 + lane * 4;
    float yv[4], xv[4];
    if constexpr (__is_same(TY, float)) {
      float4 t = *(const float4*)(y + idx);
      yv[0] = t.x; yv[1] = t.y; yv[2] = t.z; yv[3] = t.w;
    } else {
      bf16x4 t = *(const bf16x4*)(y + idx);
#pragma unroll
      for (int i = 0; i < 4; ++i) yv[i] = (float)t[i];
    }
    if constexpr (__is_same(TR, float)) {
      float4 t = *(const float4*)(x + idx);
      xv[0] = t.x; xv[1] = t.y; xv[2] = t.z; xv[3] = t.w;
    } else {
      bf16x4 t = *(const bf16x4*)(x + idx);
#pragma unroll
      for (int i = 0; i < 4; ++i) xv[i] = (float)t[i];
    }
    if (Y2 != nullptr) {
      float4 t2 = *(const float4*)(Y2 + (size_t)row * 768 + idx);
      xv[0] += t2.x; xv[1] += t2.y; xv[2] += t2.z; xv[3] += t2.w;
    }
#pragma unroll
    for (int i = 0; i < 4; ++i) {
      float t = yv[i] + xv[i];
      v[c * 4 + i] = t; s += t; s2 += t * t;
    }
  }
#pragma unroll
  for (int off = 32; off > 0; off >>= 1) { s += __shfl_xor(s, off); s2 += __shfl_xor(s2, off); }
  float mean = s * (1.f / 768.f);
  float var = fmaxf(s2 * (1.f / 768.f) - mean * mean, 0.f);
  float inv = rsqrtf(var + 1e-12f);
  TO* o = out + (size_t)row * 768;
#pragma unroll
  for (int c = 0; c < 3; ++c) {
    int idx = c * 256 + lane * 4;
    float4 gv = *(const float4*)(g + idx);
    float4 bv = *(const float4*)(b + idx);
    float r0 = (v[c * 4 + 0] - mean) * inv * gv.x + bv.x;
    float r1 = (v[c * 4 + 1] - mean) * inv * gv.y + bv.y;
    float r2 = (v[c * 4 + 2] - mean) * inv * gv.z + bv.z;
    float r3 = (v[c * 4 + 3] - mean) * inv * gv.w + bv.w;
    if constexpr (__is_same(TO, float)) {
      float4 ov = {r0, r1, r2, r3};
      *(float4*)(o + idx) = ov;
    } else {
      bf16x4 ov;
      ov[0] = (bf16)r0; ov[1] = (bf16)r1; ov[2] = (bf16)r2; ov[3] = (bf16)r3;
      *(bf16x4*)(o + idx) = ov;
    }
  }
}

// ---------------------------------------------------------------------------
extern "C" void kernel_launch(void* const* d_in, const int* in_sizes, int n_in,
                              void* d_out, int out_size, void* d_ws, size_t ws_size,
                              hipStream_t stream) {
  (void)in_sizes; (void)n_in; (void)out_size; (void)ws_size;
  const float* X     = (const float*)d_in[0];
  const float* tag   = (const float*)d_in[1];
  const float* sa_wq = (const float*)d_in[2];
  const float* sa_bq = (const float*)d_in[3];
  const float* sa_wk = (const float*)d_in[4];
  const float* sa_bk = (const float*)d_in[5];
  const float* sa_wv = (const float*)d_in[6];
  const float* sa_bv = (const float*)d_in[7];
  const float* sa_wo = (const float*)d_in[8];
  const float* sa_bo = (const float*)d_in[9];
  const float* sa_lg = (const float*)d_in[10];
  const float* sa_lb = (const float*)d_in[11];
  const float* ca_wq = (const float*)d_in[12];
  const float* ca_bq = (const float*)d_in[13];
  const float* ca_wk = (const float*)d_in[14];
  const float* ca_bk = (const float*)d_in[15];
  const float* ca_wv = (const float*)d_in[16];
  const float* ca_bv = (const float*)d_in[17];
  const float* ca_wo = (const float*)d_in[18];
  const float* ca_bo = (const float*)d_in[19];
  const float* ca_lg = (const float*)d_in[20];
  const float* ca_lb = (const float*)d_in[21];
  const float* ff_w1 = (const float*)d_in[22];
  const float* ff_b1 = (const float*)d_in[23];
  const float* ff_w2 = (const float*)d_in[24];
  const float* ff_b2 = (const float*)d_in[25];
  const float* ff_lg = (const float*)d_in[26];
  const float* ff_lb = (const float*)d_in[27];

  float* outf = (float*)d_out;
  bf16* outb = (bf16*)d_out;
  const size_t SLOT = (size_t)4096 * 768;

  // ---- ws: 34.60 MB ----
  bf16* BIG   = (bf16*)d_ws;                    // 4096x2304 (3 SLOTs)
  bf16* slotA = BIG + (size_t)4096 * 2304;      // residual chain
  bf16* Wall  = slotA + SLOT;                   // 3072x768
  bf16* W2    = Wall + (size_t)3072 * 768;      // 768x3072
  bf16* tagp  = W2;
  bf16* k2v2  = W2 + (size_t)128 * 768;
  float* bQKV = (float*)(W2 + (size_t)128 * 768 + (size_t)128 * 1536);
  float* bKV2 = bQKV + 2304;
  float* P1   = (float*)(BIG + 2 * SLOT);       // ff2 split-K partial (3rd SLOT)
  bf16*  Xb   = outb + SLOT;                    // X bf16, 2nd half of d_out

  dim3 blk(256);

  k_prep_all<<<dim3(1935), blk, 0, stream>>>(sa_bq, sa_bk, sa_bv, ca_bk, ca_bv, tag, X,
                                             bQKV, bKV2, tagp, Xb);

  // ---- self-attention ----
  k_transpose4<<<dim3(12, 12, 4), blk, 0, stream>>>(sa_wq, sa_wk, sa_wv, sa_wo, Wall);
  k_gemm<128, 64, 2, false><<<dim3(32, 36), blk, 0, stream>>>(Xb, Wall, bQKV, BIG, nullptr,
                                                              2304, 768, 768, 0);  // QKV
  k_attn_mfma<<<dim3(32, 24), blk, 0, stream>>>(BIG, 2304, BIG + 768, BIG + 1536, 2304,
                                                outb, 2048, 2048, (long long)2048 * 2304, 50);
  k_gemm<64, 64, 2, false><<<dim3(64, 12), blk, 0, stream>>>(outb, Wall + (size_t)2304 * 768,
                                                             sa_bo, slotA, nullptr,
                                                             768, 768, 768, 0);  // y1
  k_transpose4<<<dim3(12, 12, 4), blk, 0, stream>>>(ca_wq, ca_wk, ca_wv, ca_wo, Wall);
  k_add_ln<bf16, float, bf16><<<dim3(1024), blk, 0, stream>>>(slotA, X, nullptr, sa_lg, sa_lb, slotA);

  // ---- cross-attention ----
  // Q2 (z=0) + K2V2 (z=1, 48 blocks) in one dispatch.
  k_gemm_q2kv<<<dim3(64, 12, 2), blk, 0, stream>>>(slotA, Wall, ca_bq, BIG,
                                                   tagp, Wall + (size_t)768 * 768, bKV2, k2v2);
  k_attn_mfma<<<dim3(32, 24), blk, 0, stream>>>(BIG, 768, k2v2, k2v2 + 768, 1536,
                                                outb, 2048, 64, 0, -1);
  k_gemm<64, 64, 2, false><<<dim3(64, 12), blk, 0, stream>>>(outb, Wall + (size_t)2304 * 768,
                                                             ca_bo, BIG + SLOT, nullptr,
                                                             768, 768, 768, 0);  // y2
  k_add_ln<bf16, bf16, bf16><<<dim3(1024), blk, 0, stream>>>(BIG + SLOT, slotA, nullptr,
                                                             ca_lg, ca_lb, slotA);

  // ---- FFN: 2 M-chunks of 2048 rows via BIG (inter = first 2 SLOTs) ----
  k_transpose_ff<<<dim3(48, 12, 2), blk, 0, stream>>>(ff_w1, ff_w2, Wall, W2);
  for (int mc = 0; mc < 2; ++mc) {
    const bf16* a2 = slotA + (size_t)mc * 2048 * 768;
    float* yo = outf + (size_t)mc * 2048 * 768;
    k_gemm<128, 64, 2, false><<<dim3(16, 48), blk, 0, stream>>>(a2, Wall, ff_b1, BIG, nullptr,
                                                                3072, 768, 768, 1);  // gelu inter
    // ff2 split-K x2: z=0 -> yo (+bias), z=1 -> P1 (raw); summed in add_ln.
    k_gemm<64, 64, 2, true><<<dim3(32, 12, 2), blk, 0, stream>>>(BIG, W2, ff_b2, yo, P1,
                                                                 768, 1536, 3072, 0);
    k_add_ln<float, bf16, float><<<dim3(512), blk, 0, stream>>>(yo, a2, P1, ff_lg, ff_lb, yo);
  }
}